// Round 6
// baseline (3521.189 us; speedup 1.0000x reference)
//
#include <hip/hip_runtime.h>
#include <cstddef>
#include <cstdint>

constexpr int B_ = 8, P_ = 4096, K_ = 20, H_ = 64, C_ = 40;
constexpr int NPT = B_ * P_;
constexpr int NSEG = 8, SEGLEN = P_ / NSEG;   // 512 candidates per segment
#define NEG_SLOPE 0.2f

typedef unsigned long long u64;
typedef unsigned int u32;
typedef unsigned short u16;
typedef float v2f __attribute__((ext_vector_type(2)));

__device__ inline const float* uniform_ptr(const float* p) {
    uint64_t v = (uint64_t)p;
    u32 lo = __builtin_amdgcn_readfirstlane((u32)v);
    u32 hi = __builtin_amdgcn_readfirstlane((u32)(v >> 32));
    return (const float*)(((uint64_t)hi << 32) | lo);
}

// ---------------------------------------------------------------- d2 = sum(x*x)
template <int D>
__global__ __launch_bounds__(256) void d2_kernel(const float* __restrict__ x,
                                                 float* __restrict__ d2) {
    int i = blockIdx.x * 256 + threadIdx.x;
    if (i >= NPT) return;
    const float* r = x + (size_t)i * D;
    float s = 0.f;
    if constexpr (D % 4 == 0) {
#pragma unroll
        for (int d = 0; d < D; d += 4) {
            float4 v = *(const float4*)(r + d);
            s += v.x * v.x + v.y * v.y + v.z * v.z + v.w * v.w;
        }
    } else {
#pragma unroll
        for (int d = 0; d < D; ++d) { float v = r[d]; s += v * v; }
    }
    d2[i] = s;
}

// ---------------------------------------------------------------- knn segment pass
// Wave = 64 queries (features in VGPRs); candidates wave-uniform.
// Exact top-20 kept as SORTED ascending u64 keys (dist_bits<<32 | j_batch);
// insert = branch-gated bubble pass (cmp + 4 cndmask per slot, shared vcc).
// Displaced max falls off the end; non-qualifying key is a natural no-op.
template <int D>
__global__
__attribute__((amdgpu_flat_work_group_size(64, 64)))
__attribute__((amdgpu_waves_per_eu(3, 4)))
void knn_seg_kernel(const float* __restrict__ x,
                    const float* __restrict__ d2,
                    u32* __restrict__ segd,
                    u16* __restrict__ segj) {
    int qg  = blockIdx.x >> 3;        // /NSEG
    int seg = blockIdx.x & (NSEG - 1);
    int b   = qg >> 6;
    int lane = threadIdx.x;
    int ql  = ((qg & 63) << 6) + lane;          // query id within batch
    int q   = (b << 12) + ql;                   // global query id

    const float* xb  = x  + (size_t)b * P_ * D;
    const float* d2b = d2 + (size_t)b * P_;
    const float* xs  = uniform_ptr(xb);
    const float* d2s = uniform_ptr(d2b);

    float qf[D];
#pragma unroll
    for (int d = 0; d < D; ++d) qf[d] = xb[(size_t)ql * D + d];
    float qd2 = d2b[ql];

    u64 a[K_];
#pragma unroll
    for (int s = 0; s < K_; ++s)
        a[s] = (0x7F800000ULL << 32) + (u64)s;   // ascending distinct sentinels (> any real key)

    int j0 = seg * SEGLEN;
    for (int j = j0; j < j0 + SEGLEN; ++j) {
        float dist;
        if constexpr (D == 3) {
            float a0 = qf[0] * xs[j * 3];
            float a1 = qf[1] * xs[j * 3 + 1];
            float a2 = qf[2] * xs[j * 3 + 2];
            dist = (qd2 + d2s[j]) - 2.f * (a0 + a1 + a2);
        } else {
            v2f acc0 = {0.f, 0.f}, acc1 = {0.f, 0.f};
            const v2f* cp = (const v2f*)(xs + (size_t)j * D);
#pragma unroll
            for (int d4 = 0; d4 < D / 4; ++d4) {
                v2f c0 = cp[d4 * 2], c1 = cp[d4 * 2 + 1];
                v2f q0 = {qf[d4 * 4 + 0], qf[d4 * 4 + 1]};
                v2f q1 = {qf[d4 * 4 + 2], qf[d4 * 4 + 3]};
                acc0 += q0 * c0;                  // v_pk_fma_f32
                acc1 += q1 * c1;
            }
            v2f acc = acc0 + acc1;
            dist = (qd2 + d2s[j]) - 2.f * (acc.x + acc.y);
        }
        if (j == ql) dist += 1e10f;              // self mask (same as reference)
        dist = fmaxf(dist, 0.0f);                // keep f32->u32 key monotonic
        u64 carry = ((u64)__float_as_uint(dist) << 32) | (u32)j;

        if (__any(carry < a[K_ - 1])) {
#pragma unroll
            for (int s = 0; s < K_; ++s) {       // sorted bubble insert
                u64 as = a[s];
                bool c = carry < as;             // one cmp shared by min & max
                a[s]  = c ? carry : as;
                carry = c ? as : carry;
            }
        }
    }

    int o = q * (NSEG * K_) + seg * K_;
#pragma unroll
    for (int s = 0; s < K_; ++s) {
        segd[o + s] = (u32)(a[s] >> 32);
        segj[o + s] = (u16)(a[s] & 0xFFFFu);
    }
}

// ---------------------------------------------------------------- merge: wave per query
// 160 keys -> exact global top-20 by (dist, idx) via 20 wave-min-reduce rounds.
__global__ __launch_bounds__(64) void knn_merge_kernel(const u32* __restrict__ segd,
                                                       const u16* __restrict__ segj,
                                                       int* __restrict__ idx) {
    int q = blockIdx.x;
    int lane = threadIdx.x;
    const u32* ds = segd + (size_t)q * (NSEG * K_);
    const u16* js = segj + (size_t)q * (NSEG * K_);

    u64 k0 = ((u64)ds[lane] << 32) | js[lane];
    u64 k1 = ((u64)ds[64 + lane] << 32) | js[64 + lane];
    u64 k2 = (lane < NSEG * K_ - 128) ? (((u64)ds[128 + lane] << 32) | js[128 + lane]) : ~0ULL;

    int base = (q >> 12) << 12;                  // b * 4096
    int* op = idx + (size_t)q * K_;
#pragma unroll
    for (int k = 0; k < K_; ++k) {
        u64 m = k0 < k1 ? k0 : k1;
        m = k2 < m ? k2 : m;
#pragma unroll
        for (int s = 1; s < 64; s <<= 1) {
            u64 o = __shfl_xor(m, s);
            m = o < m ? o : m;
        }
        // unique keys -> exactly one lane/slot matches
        if (k0 == m) { op[k] = base + (int)(m & 0xFFFFu); k0 = ~0ULL; }
        else if (k1 == m) { op[k] = base + (int)(m & 0xFFFFu); k1 = ~0ULL; }
        else if (k2 == m) { op[k] = base + (int)(m & 0xFFFFu); k2 = ~0ULL; }
    }
}

// ---------------------------------------------------------------- pack W[128,64] -> Wpk[64,128], bpk
__global__ __launch_bounds__(128) void pack_kernel(const float* __restrict__ W,
                                                   const float* __restrict__ b,
                                                   float* __restrict__ Wpk,
                                                   float* __restrict__ bpk) {
    int t = blockIdx.x * 128 + threadIdx.x;
    int d = t >> 7, h2 = t & 127;
    Wpk[t] = (h2 < 64) ? W[d * 64 + h2] : W[(64 + d) * 64 + (h2 - 64)];
    if (t < 128) bpk[t] = (t < 64) ? b[t] : 0.f;
}

// ---------------------------------------------------------------- layer-1 UV (D=3, direct)
__global__ __launch_bounds__(256) void uv3_kernel(const float* __restrict__ x,
                                                  const float* __restrict__ W,
                                                  const float* __restrict__ b,
                                                  float* __restrict__ UV) {
    int t = blockIdx.x * 256 + threadIdx.x;
    int p = t >> 7, h2 = t & 127;
    float x0 = x[p * 3], x1 = x[p * 3 + 1], x2 = x[p * 3 + 2];
    float r;
    if (h2 < 64) {
        r = b[h2] + x0 * W[h2] + x1 * W[64 + h2] + x2 * W[128 + h2];
    } else {
        int h = h2 - 64;
        r = x0 * W[192 + h] + x1 * W[256 + h] + x2 * W[320 + h];
    }
    UV[t] = r;
}

// ---------------------------------------------------------------- edge max
__global__ __launch_bounds__(256) void edgemax_kernel(const float* __restrict__ UV,
                                                      const int* __restrict__ idx,
                                                      float* __restrict__ xout) {
    int wv = threadIdx.x >> 6, lane = threadIdx.x & 63;
    int p = blockIdx.x * 4 + wv;
    const float* uvp = UV + (size_t)p * 128;
    float duv = uvp[lane] - uvp[64 + lane];
    const int* ip = idx + (size_t)p * K_;
    int jj[K_];
#pragma unroll
    for (int k = 0; k < K_; ++k) jj[k] = ip[k];
    float m = -3.4e38f;
#pragma unroll
    for (int k = 0; k < K_; ++k) {
        float vj = UV[(size_t)jj[k] * 128 + 64 + lane];
        float t = duv + vj;
        m = fmaxf(m, fmaxf(t, NEG_SLOPE * t));
    }
    xout[(size_t)p * H_ + lane] = m;
}

// ---------------------------------------------------------------- GEMM: C = act(A @ W + b)
// BK=32 (half the barriers of BK=16); LDS stride 68 kills write conflicts.
__global__ __launch_bounds__(256) void gemm_kernel(const float* __restrict__ A1,
                                                   const float* __restrict__ A2,
                                                   const float* __restrict__ A3,
                                                   int cat,
                                                   const float* __restrict__ Wm,
                                                   const float* __restrict__ bias,
                                                   float* __restrict__ Cm,
                                                   int M, int N, int Kd, int leaky) {
    __shared__ float sA[32][68];
    __shared__ float sB[32][68];

    int tid = threadIdx.x;
    int row0 = blockIdx.x * 64, col0 = blockIdx.y * 64;
    int tx = tid & 15, ty = tid >> 4;

    int lr  = tid >> 2;          // A row 0..63
    int lk4 = (tid & 3) * 4;     // A k base {0,4,8,12}
    int lkb = tid >> 4;          // B k 0..15
    int lnb = (tid & 15) * 4;    // B col

    float acc[4][4] = {};

    for (int k0 = 0; k0 < Kd; k0 += 32) {
        int arow = row0 + lr;
#pragma unroll
        for (int h = 0; h < 32; h += 16) {
            int kk = k0 + lk4 + h;
            const float* src;
            if (cat) {
                if (kk < 64)       src = A1 + (size_t)arow * 64 + kk;
                else if (kk < 128) src = A2 + (size_t)arow * 64 + (kk - 64);
                else               src = A3 + (size_t)arow * 64 + (kk - 128);
            } else {
                src = A1 + (size_t)arow * Kd + kk;
            }
            float4 av = *(const float4*)src;
            sA[lk4 + h + 0][lr] = av.x; sA[lk4 + h + 1][lr] = av.y;
            sA[lk4 + h + 2][lr] = av.z; sA[lk4 + h + 3][lr] = av.w;
        }
        int bcol = col0 + lnb;
#pragma unroll
        for (int h = 0; h < 32; h += 16) {
            float4 bv = make_float4(0.f, 0.f, 0.f, 0.f);
            if (bcol < N) bv = *(const float4*)(Wm + (size_t)(k0 + lkb + h) * N + bcol);
            *(float4*)&sB[lkb + h][lnb] = bv;
        }
        __syncthreads();

#pragma unroll
        for (int kk2 = 0; kk2 < 32; ++kk2) {
            float4 a = *(const float4*)&sA[kk2][ty * 4];
            float4 bb = *(const float4*)&sB[kk2][tx * 4];
            acc[0][0] = fmaf(a.x, bb.x, acc[0][0]); acc[0][1] = fmaf(a.x, bb.y, acc[0][1]);
            acc[0][2] = fmaf(a.x, bb.z, acc[0][2]); acc[0][3] = fmaf(a.x, bb.w, acc[0][3]);
            acc[1][0] = fmaf(a.y, bb.x, acc[1][0]); acc[1][1] = fmaf(a.y, bb.y, acc[1][1]);
            acc[1][2] = fmaf(a.y, bb.z, acc[1][2]); acc[1][3] = fmaf(a.y, bb.w, acc[1][3]);
            acc[2][0] = fmaf(a.z, bb.x, acc[2][0]); acc[2][1] = fmaf(a.z, bb.y, acc[2][1]);
            acc[2][2] = fmaf(a.z, bb.z, acc[2][2]); acc[2][3] = fmaf(a.z, bb.w, acc[2][3]);
            acc[3][0] = fmaf(a.w, bb.x, acc[3][0]); acc[3][1] = fmaf(a.w, bb.y, acc[3][1]);
            acc[3][2] = fmaf(a.w, bb.z, acc[3][2]); acc[3][3] = fmaf(a.w, bb.w, acc[3][3]);
        }
        __syncthreads();
    }

    for (int i = 0; i < 4; ++i) {
        int row = row0 + ty * 4 + i;
        for (int j = 0; j < 4; ++j) {
            int col = col0 + tx * 4 + j;
            if (col < N) {
                float v = acc[i][j] + bias[col];
                if (leaky) v = v > 0.f ? v : NEG_SLOPE * v;
                Cm[(size_t)row * N + col] = v;
            }
        }
    }
}

// ---------------------------------------------------------------- log_softmax rows of 40
__global__ __launch_bounds__(256) void lsm_kernel(float* __restrict__ out) {
    int row = blockIdx.x * 4 + (threadIdx.x >> 6);
    int lane = threadIdx.x & 63;
    float v = -3.4e38f;
    if (lane < C_) v = out[(size_t)row * C_ + lane];
    float m = v;
#pragma unroll
    for (int s = 1; s < 64; s <<= 1) m = fmaxf(m, __shfl_xor(m, s));
    float e = (lane < C_) ? expf(v - m) : 0.f;
    float sum = e;
#pragma unroll
    for (int s = 1; s < 64; s <<= 1) sum += __shfl_xor(sum, s);
    if (lane < C_) out[(size_t)row * C_ + lane] = v - m - logf(sum);
}

// ----------------------------------------------------------------
extern "C" void kernel_launch(void* const* d_in, const int* in_sizes, int n_in,
                              void* d_out, int out_size, void* d_ws, size_t ws_size,
                              hipStream_t stream) {
    const float* x   = (const float*)d_in[0];
    const float* W1  = (const float*)d_in[2];
    const float* b1  = (const float*)d_in[3];
    const float* W2  = (const float*)d_in[4];
    const float* b2  = (const float*)d_in[5];
    const float* W3  = (const float*)d_in[6];
    const float* b3  = (const float*)d_in[7];
    const float* Wl  = (const float*)d_in[8];
    const float* bl  = (const float*)d_in[9];
    const float* Wm1 = (const float*)d_in[10];
    const float* bm1 = (const float*)d_in[11];
    const float* Wm2 = (const float*)d_in[12];
    const float* bm2 = (const float*)d_in[13];
    const float* Wo  = (const float*)d_in[14];
    const float* bo  = (const float*)d_in[15];
    float* out = (float*)d_out;

    // ---- workspace layout (total 50,987,008 B — same proven footprint) ----
    char* ws = (char*)d_ws;
    float* x1   = (float*)(ws);                       // 0        .. 8,388,608
    float* x2   = (float*)(ws + 8388608);             //          .. 16,777,216
    int*   idx  = (int*)  (ws + 16777216);            //          .. 19,398,656
    float* d2   = (float*)(ws + 19398656);            //          .. 19,529,728
    float* x3   = (float*)(ws + 19529728);            //          .. 27,918,336
    float* bufA = (float*)(ws + 27918336);            // 16 MB (MLP phase)
    float* bufB = (float*)(ws + 44695552);            // 4 MB
    float* bufC = (float*)(ws + 48889856);            // 2 MB  -> end 50,987,008
    // knn phase (dead before x3/UV/bufA writes): segd over x3+bufA, segj after
    u32*   segd = (u32*)  (ws + 19529728);            // 32768*160*4 = 20,971,520 .. 40,501,248
    u16*   segj = (u16*)  (ws + 40501248);            // 32768*160*2 = 10,485,760 .. 50,987,008
    // edge phase
    float* UV   = (float*)(ws + 27918336);            // 16 MB (aliases bufA)
    float* Wpk  = (float*)(ws + 44695552);            // 32 KB (aliases bufB)
    float* bpk  = (float*)(ws + 44728320);

    const int SEG_GRID = (NPT / 64) * NSEG;           // 4096
    const int MRG_GRID = NPT;                         // wave per query

    // ---- layer 1 (D=3)
    d2_kernel<3><<<NPT / 256, 256, 0, stream>>>(x, d2);
    knn_seg_kernel<3><<<SEG_GRID, 64, 0, stream>>>(x, d2, segd, segj);
    knn_merge_kernel<<<MRG_GRID, 64, 0, stream>>>(segd, segj, idx);
    uv3_kernel<<<NPT * 128 / 256, 256, 0, stream>>>(x, W1, b1, UV);
    edgemax_kernel<<<NPT / 4, 256, 0, stream>>>(UV, idx, x1);
    // ---- layer 2 (D=64)
    d2_kernel<64><<<NPT / 256, 256, 0, stream>>>(x1, d2);
    knn_seg_kernel<64><<<SEG_GRID, 64, 0, stream>>>(x1, d2, segd, segj);
    knn_merge_kernel<<<MRG_GRID, 64, 0, stream>>>(segd, segj, idx);
    pack_kernel<<<64, 128, 0, stream>>>(W2, b2, Wpk, bpk);
    gemm_kernel<<<dim3(NPT / 64, 2), 256, 0, stream>>>(x1, nullptr, nullptr, 0,
                                                       Wpk, bpk, UV, NPT, 128, 64, 0);
    edgemax_kernel<<<NPT / 4, 256, 0, stream>>>(UV, idx, x2);
    // ---- layer 3 (D=64)
    d2_kernel<64><<<NPT / 256, 256, 0, stream>>>(x2, d2);
    knn_seg_kernel<64><<<SEG_GRID, 64, 0, stream>>>(x2, d2, segd, segj);
    knn_merge_kernel<<<MRG_GRID, 64, 0, stream>>>(segd, segj, idx);
    pack_kernel<<<64, 128, 0, stream>>>(W3, b3, Wpk, bpk);
    gemm_kernel<<<dim3(NPT / 64, 2), 256, 0, stream>>>(x2, nullptr, nullptr, 0,
                                                       Wpk, bpk, UV, NPT, 128, 64, 0);
    edgemax_kernel<<<NPT / 4, 256, 0, stream>>>(UV, idx, x3);

    // ---- MLP head in 8 row-chunks of 4096
    for (int c = 0; c < 8; ++c) {
        size_t r0 = (size_t)c * 4096;
        gemm_kernel<<<dim3(64, 16), 256, 0, stream>>>(x1 + r0 * 64, x2 + r0 * 64, x3 + r0 * 64,
                                                      1, Wl, bl, bufA, 4096, 1024, 192, 1);
        gemm_kernel<<<dim3(64, 4), 256, 0, stream>>>(bufA, nullptr, nullptr,
                                                     0, Wm1, bm1, bufB, 4096, 256, 1024, 1);
        gemm_kernel<<<dim3(64, 2), 256, 0, stream>>>(bufB, nullptr, nullptr,
                                                     0, Wm2, bm2, bufC, 4096, 128, 256, 1);
        gemm_kernel<<<dim3(64, 1), 256, 0, stream>>>(bufC, nullptr, nullptr,
                                                     0, Wo, bo, out + r0 * C_, 4096, 40, 128, 0);
    }
    lsm_kernel<<<NPT / 4, 256, 0, stream>>>(out);
}

// Round 7
// 2642.721 us; speedup vs baseline: 1.3324x; 1.3324x over previous
//
#include <hip/hip_runtime.h>
#include <cstddef>
#include <cstdint>

constexpr int B_ = 8, P_ = 4096, K_ = 20, H_ = 64, C_ = 40;
constexpr int NPT = B_ * P_;
constexpr int NSEG = 4, SEGLEN = P_ / NSEG;   // layer-1 knn only
#define NEG_SLOPE 0.2f

typedef unsigned long long u64;
typedef unsigned int u32;
typedef float v2f __attribute__((ext_vector_type(2)));

__device__ inline const float* uniform_ptr(const float* p) {
    uint64_t v = (uint64_t)p;
    u32 lo = __builtin_amdgcn_readfirstlane((u32)v);
    u32 hi = __builtin_amdgcn_readfirstlane((u32)(v >> 32));
    return (const float*)(((uint64_t)hi << 32) | lo);
}

// ---------------------------------------------------------------- d2 = sum(x*x)
template <int D>
__global__ __launch_bounds__(256) void d2_kernel(const float* __restrict__ x,
                                                 float* __restrict__ d2) {
    int i = blockIdx.x * 256 + threadIdx.x;
    if (i >= NPT) return;
    const float* r = x + (size_t)i * D;
    float s = 0.f;
    if constexpr (D % 4 == 0) {
#pragma unroll
        for (int d = 0; d < D; d += 4) {
            float4 v = *(const float4*)(r + d);
            s += v.x * v.x + v.y * v.y + v.z * v.z + v.w * v.w;
        }
    } else {
#pragma unroll
        for (int d = 0; d < D; ++d) { float v = r[d]; s += v * v; }
    }
    d2[i] = s;
}

// ---------------------------------------------------------------- layer-1 knn (D=3), R5-proven
template <int D>
__global__
__attribute__((amdgpu_flat_work_group_size(64, 64)))
__attribute__((amdgpu_waves_per_eu(1, 2)))
void knn_seg_kernel(const float* __restrict__ x,
                    const float* __restrict__ d2,
                    u64* __restrict__ seglist) {
    int qg  = blockIdx.x / NSEG;
    int seg = blockIdx.x % NSEG;
    int b   = qg >> 6;
    int lane = threadIdx.x;
    int ql  = ((qg & 63) << 6) + lane;
    int q   = (b << 12) + ql;

    const float* xb  = x  + (size_t)b * P_ * D;
    const float* d2b = d2 + (size_t)b * P_;
    const float* xs  = uniform_ptr(xb);
    const float* d2s = uniform_ptr(d2b);

    float qf[D];
#pragma unroll
    for (int d = 0; d < D; ++d) qf[d] = xb[(size_t)ql * D + d];
    float qd2 = d2b[ql];

    u64 lst[K_];
#pragma unroll
    for (int s = 0; s < K_; ++s)
        lst[s] = (0x7F800000ULL << 32) | (u64)(0xFFFFFFFFu - s);   // distinct sentinels
    u64 kmax = (0x7F800000ULL << 32) | 0xFFFFFFFFULL;

    u64 p0 = ~0ULL, p1 = ~0ULL;
    int pcnt = 0;

    int j0 = seg * SEGLEN;
    for (int j = j0; j < j0 + SEGLEN; ++j) {
        float dist;
        if constexpr (D == 3) {
            float a0 = qf[0] * xs[j * 3];
            float a1 = qf[1] * xs[j * 3 + 1];
            float a2 = qf[2] * xs[j * 3 + 2];
            dist = (qd2 + d2s[j]) - 2.f * (a0 + a1 + a2);
        } else {
            v2f acc0 = {0.f, 0.f}, acc1 = {0.f, 0.f};
            const v2f* cp = (const v2f*)(xs + (size_t)j * D);
#pragma unroll
            for (int d4 = 0; d4 < D / 4; ++d4) {
                v2f c0 = cp[d4 * 2], c1 = cp[d4 * 2 + 1];
                v2f q0 = {qf[d4 * 4 + 0], qf[d4 * 4 + 1]};
                v2f q1 = {qf[d4 * 4 + 2], qf[d4 * 4 + 3]};
                acc0 += q0 * c0;
                acc1 += q1 * c1;
            }
            v2f acc = acc0 + acc1;
            dist = (qd2 + d2s[j]) - 2.f * (acc.x + acc.y);
        }
        if (j == ql) dist += 1e10f;
        dist = fmaxf(dist, 0.0f);
        u64 key = ((u64)__float_as_uint(dist) << 32) | (u32)j;

        bool pass = key < kmax;
        p1 = pass ? p0 : p1;
        p0 = pass ? key : p0;
        pcnt = pass ? pcnt + 1 : pcnt;

        if (__any(pcnt >= 2)) {
            u64 e0 = p1, e1 = p0;
#pragma unroll
            for (int t = 0; t < 2; ++t) {
                u64 key2 = (t == 0) ? e0 : e1;
                bool ins = key2 < kmax;
                if (__any(ins)) {
                    u64 km = kmax;
#pragma unroll
                    for (int s = 0; s < K_; ++s)
                        lst[s] = (ins && lst[s] == km) ? key2 : lst[s];
                    u64 m = lst[0];
#pragma unroll
                    for (int s = 1; s < K_; ++s) m = lst[s] > m ? lst[s] : m;
                    kmax = m;
                }
            }
            p0 = ~0ULL; p1 = ~0ULL; pcnt = 0;
        }
    }
    {
        u64 e0 = p1, e1 = p0;
#pragma unroll
        for (int t = 0; t < 2; ++t) {
            u64 key2 = (t == 0) ? e0 : e1;
            bool ins = key2 < kmax;
            if (__any(ins)) {
                u64 km = kmax;
#pragma unroll
                for (int s = 0; s < K_; ++s)
                    lst[s] = (ins && lst[s] == km) ? key2 : lst[s];
                u64 m = lst[0];
#pragma unroll
                for (int s = 1; s < K_; ++s) m = lst[s] > m ? lst[s] : m;
                kmax = m;
            }
        }
    }

    u64* outp = seglist + ((size_t)q * NSEG + seg) * K_;
#pragma unroll
    for (int s = 0; s < K_; ++s) outp[s] = lst[s];
}

// ---------------------------------------------------------------- layer-1 merge: wave per query, 80 keys
__global__ __launch_bounds__(64) void knn_mergeu64_kernel(const u64* __restrict__ seglist,
                                                          int* __restrict__ idx) {
    int q = blockIdx.x;
    int lane = threadIdx.x;
    const u64* src = seglist + (size_t)q * (NSEG * K_);
    u64 k0 = src[lane];
    u64 k1 = (lane < NSEG * K_ - 64) ? src[64 + lane] : ~0ULL;
    int base = (q >> 12) << 12;
    int* op = idx + (size_t)q * K_;
#pragma unroll 1
    for (int k = 0; k < K_; ++k) {
        u64 m = k0 < k1 ? k0 : k1;
#pragma unroll
        for (int s = 1; s < 64; s <<= 1) {
            u64 o = __shfl_xor(m, s);
            m = o < m ? o : m;
        }
        if (k0 == m) k0 = ~0ULL;
        else if (k1 == m) k1 = ~0ULL;
        if (lane == 0) op[k] = base + (int)(m & 0xFFFFFFFFu);
    }
}

// ---------------------------------------------------------------- fused knn (D=64):
// block = 64 queries; per 64-cand chunk: dist tile via LDS GEMM (4x4 microtile),
// then 4-lanes-per-query exact sorted-top20 with f64 fmin/fmax bubble insert.
__global__ __launch_bounds__(256) void knnf64_kernel(const float* __restrict__ x,
                                                     const float* __restrict__ d2,
                                                     int* __restrict__ idx) {
    __shared__ float sQT[64][68];   // [d][q]
    __shared__ float sCT[64][68];   // [d][c]
    __shared__ float sD[64][68];    // [q][c]

    int b = blockIdx.y;
    int q0 = blockIdx.x * 64;
    const float* xc  = x + (size_t)b * P_ * 64;
    const float* d2b = d2 + (size_t)b * P_;

    int t = threadIdx.x;
    int ty = t >> 4, tx = t & 15;
    int w = t >> 6, ln = t & 63;
    int qs = w * 16 + (ln >> 2);     // selection: query row in tile
    int cs = ln & 3;                 // selection: candidate sub-stream

    // stage Q^T once
    {
        int qq = t & 63, dg = (t >> 6) * 16;
        const float4* src = (const float4*)(xc + (size_t)(q0 + qq) * 64 + dg);
        float v[16];
        *(float4*)&v[0]  = src[0];
        *(float4*)&v[4]  = src[1];
        *(float4*)&v[8]  = src[2];
        *(float4*)&v[12] = src[3];
#pragma unroll
        for (int i2 = 0; i2 < 16; ++i2) sQT[dg + i2][qq] = v[i2];
    }
    float qd2i[4];
#pragma unroll
    for (int i = 0; i < 4; ++i) qd2i[i] = d2b[q0 + ty * 4 + i];

    // sorted ascending top-20 as positive doubles (bitwise == (dist_bits<<32)|cand)
    double a[K_];
#pragma unroll
    for (int s = 0; s < K_; ++s)
        a[s] = __longlong_as_double((0x7F7FFFFFLL << 32) | (long long)(0xFFFF0000u + s));
    const double BIG = __longlong_as_double((0x7F7FFFFFLL << 32) | 0xFFFFFFF0LL);

#pragma unroll 1
    for (int c0 = 0; c0 < P_; c0 += 64) {
        __syncthreads();   // prev GEMM sCT-reads + prev selection sD-reads complete
        {
            int cc = t & 63, dg = (t >> 6) * 16;
            const float4* src = (const float4*)(xc + (size_t)(c0 + cc) * 64 + dg);
            float v[16];
            *(float4*)&v[0]  = src[0];
            *(float4*)&v[4]  = src[1];
            *(float4*)&v[8]  = src[2];
            *(float4*)&v[12] = src[3];
#pragma unroll
            for (int i2 = 0; i2 < 16; ++i2) sCT[dg + i2][cc] = v[i2];
        }
        __syncthreads();   // sCT (and first-iter sQT) ready

        float acc[4][4] = {};
#pragma unroll
        for (int kk = 0; kk < 64; ++kk) {
            float4 aq = *(const float4*)&sQT[kk][ty * 4];
            float4 bc = *(const float4*)&sCT[kk][tx * 4];
            acc[0][0] = fmaf(aq.x, bc.x, acc[0][0]); acc[0][1] = fmaf(aq.x, bc.y, acc[0][1]);
            acc[0][2] = fmaf(aq.x, bc.z, acc[0][2]); acc[0][3] = fmaf(aq.x, bc.w, acc[0][3]);
            acc[1][0] = fmaf(aq.y, bc.x, acc[1][0]); acc[1][1] = fmaf(aq.y, bc.y, acc[1][1]);
            acc[1][2] = fmaf(aq.y, bc.z, acc[1][2]); acc[1][3] = fmaf(aq.y, bc.w, acc[1][3]);
            acc[2][0] = fmaf(aq.z, bc.x, acc[2][0]); acc[2][1] = fmaf(aq.z, bc.y, acc[2][1]);
            acc[2][2] = fmaf(aq.z, bc.z, acc[2][2]); acc[2][3] = fmaf(aq.z, bc.w, acc[2][3]);
            acc[3][0] = fmaf(aq.w, bc.x, acc[3][0]); acc[3][1] = fmaf(aq.w, bc.y, acc[3][1]);
            acc[3][2] = fmaf(aq.w, bc.z, acc[3][2]); acc[3][3] = fmaf(aq.w, bc.w, acc[3][3]);
        }
        float cd2j[4];
#pragma unroll
        for (int j = 0; j < 4; ++j) cd2j[j] = d2b[c0 + tx * 4 + j];
        bool diag = (q0 == c0);
#pragma unroll
        for (int i = 0; i < 4; ++i) {
            float dd[4];
#pragma unroll
            for (int j = 0; j < 4; ++j) {
                float v = (qd2i[i] + cd2j[j]) - 2.f * acc[i][j];
                if (diag && (ty * 4 + i == tx * 4 + j)) v += 1e10f;   // self mask
                dd[j] = fmaxf(v, 0.f);
            }
            *(float4*)&sD[ty * 4 + i][tx * 4] = make_float4(dd[0], dd[1], dd[2], dd[3]);
        }
        __syncthreads();   // sD ready

        // selection: 16 evals/lane, unconditional f64 bubble insert (2 instr/slot)
#pragma unroll
        for (int u = 0; u < 16; ++u) {
            int c = cs + u * 4;
            float dv = sD[qs][c];
            u64 kb = ((u64)__float_as_uint(dv) << 32) | (u32)(c0 + c);
            double carry = __longlong_as_double((long long)kb);
#pragma unroll
            for (int s = 0; s < K_; ++s) {
                double as = a[s];
                a[s]  = fmin(carry, as);
                carry = fmax(carry, as);
            }
        }
    }

    // merge the 4 sub-stream lists per query: 20 rounds pop-min
    int* op = idx + ((size_t)(b * P_ + q0 + qs)) * K_;
#pragma unroll 1
    for (int k = 0; k < K_; ++k) {
        double v = a[0];
        double v1 = __shfl_xor(v, 1);
        v = fmin(v, v1);
        double v2 = __shfl_xor(v, 2);
        v = fmin(v, v2);
        bool win = (__double_as_longlong(a[0]) == __double_as_longlong(v));
#pragma unroll
        for (int s = 0; s < K_ - 1; ++s) a[s] = win ? a[s + 1] : a[s];
        a[K_ - 1] = win ? BIG : a[K_ - 1];
        if (cs == 0)
            op[k] = b * P_ + (int)(__double_as_longlong(v) & 0xFFFFFFFFLL);
    }
}

// ---------------------------------------------------------------- pack W[128,64] -> Wpk[64,128], bpk
__global__ __launch_bounds__(128) void pack_kernel(const float* __restrict__ W,
                                                   const float* __restrict__ b,
                                                   float* __restrict__ Wpk,
                                                   float* __restrict__ bpk) {
    int t = blockIdx.x * 128 + threadIdx.x;
    int d = t >> 7, h2 = t & 127;
    Wpk[t] = (h2 < 64) ? W[d * 64 + h2] : W[(64 + d) * 64 + (h2 - 64)];
    if (t < 128) bpk[t] = (t < 64) ? b[t] : 0.f;
}

// ---------------------------------------------------------------- layer-1 UV (D=3, direct)
__global__ __launch_bounds__(256) void uv3_kernel(const float* __restrict__ x,
                                                  const float* __restrict__ W,
                                                  const float* __restrict__ b,
                                                  float* __restrict__ UV) {
    int t = blockIdx.x * 256 + threadIdx.x;
    int p = t >> 7, h2 = t & 127;
    float x0 = x[p * 3], x1 = x[p * 3 + 1], x2 = x[p * 3 + 2];
    float r;
    if (h2 < 64) {
        r = b[h2] + x0 * W[h2] + x1 * W[64 + h2] + x2 * W[128 + h2];
    } else {
        int h = h2 - 64;
        r = x0 * W[192 + h] + x1 * W[256 + h] + x2 * W[320 + h];
    }
    UV[t] = r;
}

// ---------------------------------------------------------------- edge max
__global__ __launch_bounds__(256) void edgemax_kernel(const float* __restrict__ UV,
                                                      const int* __restrict__ idx,
                                                      float* __restrict__ xout) {
    int wv = threadIdx.x >> 6, lane = threadIdx.x & 63;
    int p = blockIdx.x * 4 + wv;
    const float* uvp = UV + (size_t)p * 128;
    float duv = uvp[lane] - uvp[64 + lane];
    const int* ip = idx + (size_t)p * K_;
    int jj[K_];
#pragma unroll
    for (int k = 0; k < K_; ++k) jj[k] = ip[k];
    float m = -3.4e38f;
#pragma unroll
    for (int k = 0; k < K_; ++k) {
        float vj = UV[(size_t)jj[k] * 128 + 64 + lane];
        float t = duv + vj;
        m = fmaxf(m, fmaxf(t, NEG_SLOPE * t));
    }
    xout[(size_t)p * H_ + lane] = m;
}

// ---------------------------------------------------------------- GEMM 64x64 (BK=32), stride-68 LDS
__global__ __launch_bounds__(256) void gemm_kernel(const float* __restrict__ A1,
                                                   const float* __restrict__ A2,
                                                   const float* __restrict__ A3,
                                                   int cat,
                                                   const float* __restrict__ Wm,
                                                   const float* __restrict__ bias,
                                                   float* __restrict__ Cm,
                                                   int M, int N, int Kd, int leaky) {
    __shared__ float sA[32][68];
    __shared__ float sB[32][68];

    int tid = threadIdx.x;
    int row0 = blockIdx.x * 64, col0 = blockIdx.y * 64;
    int tx = tid & 15, ty = tid >> 4;

    int lr  = tid >> 2;
    int lk4 = (tid & 3) * 4;
    int lkb = tid >> 4;
    int lnb = (tid & 15) * 4;

    float acc[4][4] = {};

    for (int k0 = 0; k0 < Kd; k0 += 32) {
        int arow = row0 + lr;
#pragma unroll
        for (int h = 0; h < 32; h += 16) {
            int kk = k0 + lk4 + h;
            const float* src;
            if (cat) {
                if (kk < 64)       src = A1 + (size_t)arow * 64 + kk;
                else if (kk < 128) src = A2 + (size_t)arow * 64 + (kk - 64);
                else               src = A3 + (size_t)arow * 64 + (kk - 128);
            } else {
                src = A1 + (size_t)arow * Kd + kk;
            }
            float4 av = *(const float4*)src;
            sA[lk4 + h + 0][lr] = av.x; sA[lk4 + h + 1][lr] = av.y;
            sA[lk4 + h + 2][lr] = av.z; sA[lk4 + h + 3][lr] = av.w;
        }
        int bcol = col0 + lnb;
#pragma unroll
        for (int h = 0; h < 32; h += 16) {
            float4 bv = make_float4(0.f, 0.f, 0.f, 0.f);
            if (bcol < N) bv = *(const float4*)(Wm + (size_t)(k0 + lkb + h) * N + bcol);
            *(float4*)&sB[lkb + h][lnb] = bv;
        }
        __syncthreads();

#pragma unroll
        for (int kk2 = 0; kk2 < 32; ++kk2) {
            float4 a = *(const float4*)&sA[kk2][ty * 4];
            float4 bb = *(const float4*)&sB[kk2][tx * 4];
            acc[0][0] = fmaf(a.x, bb.x, acc[0][0]); acc[0][1] = fmaf(a.x, bb.y, acc[0][1]);
            acc[0][2] = fmaf(a.x, bb.z, acc[0][2]); acc[0][3] = fmaf(a.x, bb.w, acc[0][3]);
            acc[1][0] = fmaf(a.y, bb.x, acc[1][0]); acc[1][1] = fmaf(a.y, bb.y, acc[1][1]);
            acc[1][2] = fmaf(a.y, bb.z, acc[1][2]); acc[1][3] = fmaf(a.y, bb.w, acc[1][3]);
            acc[2][0] = fmaf(a.z, bb.x, acc[2][0]); acc[2][1] = fmaf(a.z, bb.y, acc[2][1]);
            acc[2][2] = fmaf(a.z, bb.z, acc[2][2]); acc[2][3] = fmaf(a.z, bb.w, acc[2][3]);
            acc[3][0] = fmaf(a.w, bb.x, acc[3][0]); acc[3][1] = fmaf(a.w, bb.y, acc[3][1]);
            acc[3][2] = fmaf(a.w, bb.z, acc[3][2]); acc[3][3] = fmaf(a.w, bb.w, acc[3][3]);
        }
        __syncthreads();
    }

    for (int i = 0; i < 4; ++i) {
        int row = row0 + ty * 4 + i;
        for (int j = 0; j < 4; ++j) {
            int col = col0 + tx * 4 + j;
            if (col < N) {
                float v = acc[i][j] + bias[col];
                if (leaky) v = v > 0.f ? v : NEG_SLOPE * v;
                Cm[(size_t)row * N + col] = v;
            }
        }
    }
}

// ---------------------------------------------------------------- GEMM 128x128 (BK=16), 8x8 microtile
__global__ __launch_bounds__(256) void gemm128_kernel(const float* __restrict__ A1,
                                                      const float* __restrict__ A2,
                                                      const float* __restrict__ A3,
                                                      int cat,
                                                      const float* __restrict__ Wm,
                                                      const float* __restrict__ bias,
                                                      float* __restrict__ Cm,
                                                      int M, int N, int Kd, int leaky) {
    __shared__ float sA[16][132];
    __shared__ float sB[16][132];

    int t = threadIdx.x;
    int row0 = blockIdx.x * 128, col0 = blockIdx.y * 128;
    int ty = t >> 4, tx = t & 15;

    float acc[8][8] = {};

    for (int k0 = 0; k0 < Kd; k0 += 16) {
        // per-k0 single source (BK=16 divides the 64-boundaries)
        const float* srcA; int koff, lda;
        if (cat) {
            lda = 64;
            if (k0 < 64)       { srcA = A1; koff = k0; }
            else if (k0 < 128) { srcA = A2; koff = k0 - 64; }
            else               { srcA = A3; koff = k0 - 128; }
        } else { srcA = A1; koff = k0; lda = Kd; }

#pragma unroll
        for (int h = 0; h < 2; ++h) {
            int li = t * 2 + h;
            int m = li >> 2, k4 = (li & 3) * 4;
            float4 av = *(const float4*)(srcA + (size_t)(row0 + m) * lda + koff + k4);
            sA[k4 + 0][m] = av.x; sA[k4 + 1][m] = av.y;
            sA[k4 + 2][m] = av.z; sA[k4 + 3][m] = av.w;
        }
#pragma unroll
        for (int h = 0; h < 2; ++h) {
            int li = t * 2 + h;
            int kk = li >> 5, n4 = (li & 31) * 4;
            float4 bv = make_float4(0.f, 0.f, 0.f, 0.f);
            if (col0 + n4 < N) bv = *(const float4*)(Wm + (size_t)(k0 + kk) * N + col0 + n4);
            *(float4*)&sB[kk][n4] = bv;
        }
        __syncthreads();

#pragma unroll
        for (int kk = 0; kk < 16; ++kk) {
            float av[8], bv[8];
            *(float4*)&av[0] = *(const float4*)&sA[kk][ty * 4];
            *(float4*)&av[4] = *(const float4*)&sA[kk][64 + ty * 4];
            *(float4*)&bv[0] = *(const float4*)&sB[kk][tx * 4];
            *(float4*)&bv[4] = *(const float4*)&sB[kk][64 + tx * 4];
#pragma unroll
            for (int i = 0; i < 8; ++i)
#pragma unroll
                for (int j = 0; j < 8; ++j)
                    acc[i][j] = fmaf(av[i], bv[j], acc[i][j]);
        }
        __syncthreads();
    }

#pragma unroll
    for (int i = 0; i < 8; ++i) {
        int row = row0 + (i < 4 ? ty * 4 + i : 64 + ty * 4 + (i - 4));
#pragma unroll
        for (int jb = 0; jb < 2; ++jb) {
            int col = col0 + (jb == 0 ? tx * 4 : 64 + tx * 4);
            if (col < N) {
                float o[4];
#pragma unroll
                for (int j = 0; j < 4; ++j) {
                    float v = acc[i][jb * 4 + j] + bias[col + j];
                    if (leaky) v = v > 0.f ? v : NEG_SLOPE * v;
                    o[j] = v;
                }
                *(float4*)(Cm + (size_t)row * N + col) = make_float4(o[0], o[1], o[2], o[3]);
            }
        }
    }
}

// ---------------------------------------------------------------- log_softmax rows of 40
__global__ __launch_bounds__(256) void lsm_kernel(float* __restrict__ out) {
    int row = blockIdx.x * 4 + (threadIdx.x >> 6);
    int lane = threadIdx.x & 63;
    float v = -3.4e38f;
    if (lane < C_) v = out[(size_t)row * C_ + lane];
    float m = v;
#pragma unroll
    for (int s = 1; s < 64; s <<= 1) m = fmaxf(m, __shfl_xor(m, s));
    float e = (lane < C_) ? expf(v - m) : 0.f;
    float sum = e;
#pragma unroll
    for (int s = 1; s < 64; s <<= 1) sum += __shfl_xor(sum, s);
    if (lane < C_) out[(size_t)row * C_ + lane] = v - m - logf(sum);
}

// ----------------------------------------------------------------
extern "C" void kernel_launch(void* const* d_in, const int* in_sizes, int n_in,
                              void* d_out, int out_size, void* d_ws, size_t ws_size,
                              hipStream_t stream) {
    const float* x   = (const float*)d_in[0];
    const float* W1  = (const float*)d_in[2];
    const float* b1  = (const float*)d_in[3];
    const float* W2  = (const float*)d_in[4];
    const float* b2  = (const float*)d_in[5];
    const float* W3  = (const float*)d_in[6];
    const float* b3  = (const float*)d_in[7];
    const float* Wl  = (const float*)d_in[8];
    const float* bl  = (const float*)d_in[9];
    const float* Wm1 = (const float*)d_in[10];
    const float* bm1 = (const float*)d_in[11];
    const float* Wm2 = (const float*)d_in[12];
    const float* bm2 = (const float*)d_in[13];
    const float* Wo  = (const float*)d_in[14];
    const float* bo  = (const float*)d_in[15];
    float* out = (float*)d_out;

    // ---- workspace (max 50,987,008 B — proven footprint) ----
    char* ws = (char*)d_ws;
    float* x1   = (float*)(ws);                       // 8 MB
    float* x2   = (float*)(ws + 8388608);             // 8 MB
    float* x3   = (float*)(ws + 16777216);            // 8 MB
    int*   idx  = (int*)  (ws + 25165824);            // 2.62 MB
    float* d2   = (float*)(ws + 27787264);            // 128 KB
    float* bufA = (float*)(ws + 27918336);            // 16 MB (MLP phase)
    float* bufB = (float*)(ws + 44695552);            // 4 MB
    float* bufC = (float*)(ws + 48889856);            // 2 MB  -> end 50,987,008
    u64*   segl = (u64*)  (ws + 27918336);            // 20.97 MB (layer-1 knn only, dead before UV)
    float* UV   = (float*)(ws + 27918336);            // 16 MB (edge phase, aliases bufA)
    float* Wpk  = (float*)(ws + 44695552);            // 32 KB (aliases bufB)
    float* bpk  = (float*)(ws + 44728320);

    const int SEG_GRID = (NPT / 64) * NSEG;           // 2048

    // ---- layer 1 (D=3): proven seg+merge path
    d2_kernel<3><<<NPT / 256, 256, 0, stream>>>(x, d2);
    knn_seg_kernel<3><<<SEG_GRID, 64, 0, stream>>>(x, d2, segl);
    knn_mergeu64_kernel<<<NPT, 64, 0, stream>>>(segl, idx);
    uv3_kernel<<<NPT * 128 / 256, 256, 0, stream>>>(x, W1, b1, UV);
    edgemax_kernel<<<NPT / 4, 256, 0, stream>>>(UV, idx, x1);
    // ---- layer 2 (D=64): fused dist-GEMM + selection
    d2_kernel<64><<<NPT / 256, 256, 0, stream>>>(x1, d2);
    knnf64_kernel<<<dim3(P_ / 64, B_), 256, 0, stream>>>(x1, d2, idx);
    pack_kernel<<<64, 128, 0, stream>>>(W2, b2, Wpk, bpk);
    gemm_kernel<<<dim3(NPT / 64, 2), 256, 0, stream>>>(x1, nullptr, nullptr, 0,
                                                       Wpk, bpk, UV, NPT, 128, 64, 0);
    edgemax_kernel<<<NPT / 4, 256, 0, stream>>>(UV, idx, x2);
    // ---- layer 3 (D=64)
    d2_kernel<64><<<NPT / 256, 256, 0, stream>>>(x2, d2);
    knnf64_kernel<<<dim3(P_ / 64, B_), 256, 0, stream>>>(x2, d2, idx);
    pack_kernel<<<64, 128, 0, stream>>>(W3, b3, Wpk, bpk);
    gemm_kernel<<<dim3(NPT / 64, 2), 256, 0, stream>>>(x2, nullptr, nullptr, 0,
                                                       Wpk, bpk, UV, NPT, 128, 64, 0);
    edgemax_kernel<<<NPT / 4, 256, 0, stream>>>(UV, idx, x3);

    // ---- MLP head in 8 row-chunks of 4096
    for (int c = 0; c < 8; ++c) {
        size_t r0 = (size_t)c * 4096;
        gemm128_kernel<<<dim3(32, 8), 256, 0, stream>>>(x1 + r0 * 64, x2 + r0 * 64, x3 + r0 * 64,
                                                        1, Wl, bl, bufA, 4096, 1024, 192, 1);
        gemm_kernel<<<dim3(64, 4), 256, 0, stream>>>(bufA, nullptr, nullptr,
                                                     0, Wm1, bm1, bufB, 4096, 256, 1024, 1);
        gemm_kernel<<<dim3(64, 2), 256, 0, stream>>>(bufB, nullptr, nullptr,
                                                     0, Wm2, bm2, bufC, 4096, 128, 256, 1);
        gemm_kernel<<<dim3(64, 1), 256, 0, stream>>>(bufC, nullptr, nullptr,
                                                     0, Wo, bo, out + r0 * C_, 4096, 40, 128, 0);
    }
    lsm_kernel<<<NPT / 4, 256, 0, stream>>>(out);
}

// Round 8
// 2028.712 us; speedup vs baseline: 1.7357x; 1.3027x over previous
//
#include <hip/hip_runtime.h>
#include <cstddef>
#include <cstdint>

constexpr int B_ = 8, P_ = 4096, K_ = 20, H_ = 64, C_ = 40;
constexpr int NPT = B_ * P_;
constexpr int NSEG = 4, SEGLEN = P_ / NSEG;   // layer-1 knn only
#define NEG_SLOPE 0.2f

typedef unsigned long long u64;
typedef unsigned int u32;
typedef unsigned short u16;
typedef float v2f __attribute__((ext_vector_type(2)));
typedef __attribute__((ext_vector_type(8))) short bf16x8;
typedef __attribute__((ext_vector_type(4))) float f32x4;

__device__ inline const float* uniform_ptr(const float* p) {
    uint64_t v = (uint64_t)p;
    u32 lo = __builtin_amdgcn_readfirstlane((u32)v);
    u32 hi = __builtin_amdgcn_readfirstlane((u32)(v >> 32));
    return (const float*)(((uint64_t)hi << 32) | lo);
}

__device__ inline u16 f2bf(float v) {   // round-to-nearest-even bf16
    u32 bits = __float_as_uint(v);
    return (u16)((bits + 0x7FFFu + ((bits >> 16) & 1)) >> 16);
}

// ---------------------------------------------------------------- d2 = sum(x*x)
template <int D>
__global__ __launch_bounds__(256) void d2_kernel(const float* __restrict__ x,
                                                 float* __restrict__ d2) {
    int i = blockIdx.x * 256 + threadIdx.x;
    if (i >= NPT) return;
    const float* r = x + (size_t)i * D;
    float s = 0.f;
    if constexpr (D % 4 == 0) {
#pragma unroll
        for (int d = 0; d < D; d += 4) {
            float4 v = *(const float4*)(r + d);
            s += v.x * v.x + v.y * v.y + v.z * v.z + v.w * v.w;
        }
    } else {
#pragma unroll
        for (int d = 0; d < D; ++d) { float v = r[d]; s += v * v; }
    }
    d2[i] = s;
}

// ---------------------------------------------------------------- layer-1 knn (D=3), R5-proven
template <int D>
__global__
__attribute__((amdgpu_flat_work_group_size(64, 64)))
__attribute__((amdgpu_waves_per_eu(1, 2)))
void knn_seg_kernel(const float* __restrict__ x,
                    const float* __restrict__ d2,
                    u64* __restrict__ seglist) {
    int qg  = blockIdx.x / NSEG;
    int seg = blockIdx.x % NSEG;
    int b   = qg >> 6;
    int lane = threadIdx.x;
    int ql  = ((qg & 63) << 6) + lane;
    int q   = (b << 12) + ql;

    const float* xb  = x  + (size_t)b * P_ * D;
    const float* d2b = d2 + (size_t)b * P_;
    const float* xs  = uniform_ptr(xb);
    const float* d2s = uniform_ptr(d2b);

    float qf[D];
#pragma unroll
    for (int d = 0; d < D; ++d) qf[d] = xb[(size_t)ql * D + d];
    float qd2 = d2b[ql];

    u64 lst[K_];
#pragma unroll
    for (int s = 0; s < K_; ++s)
        lst[s] = (0x7F800000ULL << 32) | (u64)(0xFFFFFFFFu - s);
    u64 kmax = (0x7F800000ULL << 32) | 0xFFFFFFFFULL;

    u64 p0 = ~0ULL, p1 = ~0ULL;
    int pcnt = 0;

    int j0 = seg * SEGLEN;
    for (int j = j0; j < j0 + SEGLEN; ++j) {
        float dist;
        if constexpr (D == 3) {
            float a0 = qf[0] * xs[j * 3];
            float a1 = qf[1] * xs[j * 3 + 1];
            float a2 = qf[2] * xs[j * 3 + 2];
            dist = (qd2 + d2s[j]) - 2.f * (a0 + a1 + a2);
        } else {
            v2f acc0 = {0.f, 0.f}, acc1 = {0.f, 0.f};
            const v2f* cp = (const v2f*)(xs + (size_t)j * D);
#pragma unroll
            for (int d4 = 0; d4 < D / 4; ++d4) {
                v2f c0 = cp[d4 * 2], c1 = cp[d4 * 2 + 1];
                v2f q0 = {qf[d4 * 4 + 0], qf[d4 * 4 + 1]};
                v2f q1 = {qf[d4 * 4 + 2], qf[d4 * 4 + 3]};
                acc0 += q0 * c0;
                acc1 += q1 * c1;
            }
            v2f acc = acc0 + acc1;
            dist = (qd2 + d2s[j]) - 2.f * (acc.x + acc.y);
        }
        if (j == ql) dist += 1e10f;
        dist = fmaxf(dist, 0.0f);
        u64 key = ((u64)__float_as_uint(dist) << 32) | (u32)j;

        bool pass = key < kmax;
        p1 = pass ? p0 : p1;
        p0 = pass ? key : p0;
        pcnt = pass ? pcnt + 1 : pcnt;

        if (__any(pcnt >= 2)) {
            u64 e0 = p1, e1 = p0;
#pragma unroll
            for (int t = 0; t < 2; ++t) {
                u64 key2 = (t == 0) ? e0 : e1;
                bool ins = key2 < kmax;
                if (__any(ins)) {
                    u64 km = kmax;
#pragma unroll
                    for (int s = 0; s < K_; ++s)
                        lst[s] = (ins && lst[s] == km) ? key2 : lst[s];
                    u64 m = lst[0];
#pragma unroll
                    for (int s = 1; s < K_; ++s) m = lst[s] > m ? lst[s] : m;
                    kmax = m;
                }
            }
            p0 = ~0ULL; p1 = ~0ULL; pcnt = 0;
        }
    }
    {
        u64 e0 = p1, e1 = p0;
#pragma unroll
        for (int t = 0; t < 2; ++t) {
            u64 key2 = (t == 0) ? e0 : e1;
            bool ins = key2 < kmax;
            if (__any(ins)) {
                u64 km = kmax;
#pragma unroll
                for (int s = 0; s < K_; ++s)
                    lst[s] = (ins && lst[s] == km) ? key2 : lst[s];
                u64 m = lst[0];
#pragma unroll
                for (int s = 1; s < K_; ++s) m = lst[s] > m ? lst[s] : m;
                kmax = m;
            }
        }
    }

    u64* outp = seglist + ((size_t)q * NSEG + seg) * K_;
#pragma unroll
    for (int s = 0; s < K_; ++s) outp[s] = lst[s];
}

// ---------------------------------------------------------------- layer-1 merge
__global__ __launch_bounds__(64) void knn_mergeu64_kernel(const u64* __restrict__ seglist,
                                                          int* __restrict__ idx) {
    int q = blockIdx.x;
    int lane = threadIdx.x;
    const u64* src = seglist + (size_t)q * (NSEG * K_);
    u64 k0 = src[lane];
    u64 k1 = (lane < NSEG * K_ - 64) ? src[64 + lane] : ~0ULL;
    int base = (q >> 12) << 12;
    int* op = idx + (size_t)q * K_;
#pragma unroll 1
    for (int k = 0; k < K_; ++k) {
        u64 m = k0 < k1 ? k0 : k1;
#pragma unroll
        for (int s = 1; s < 64; s <<= 1) {
            u64 o = __shfl_xor(m, s);
            m = o < m ? o : m;
        }
        if (k0 == m) k0 = ~0ULL;
        else if (k1 == m) k1 = ~0ULL;
        if (lane == 0) op[k] = base + (int)(m & 0xFFFFFFFFu);
    }
}

// ---------------------------------------------------------------- fused knn (D=64), R7-proven
__global__ __launch_bounds__(256) void knnf64_kernel(const float* __restrict__ x,
                                                     const float* __restrict__ d2,
                                                     int* __restrict__ idx) {
    __shared__ float sQT[64][68];
    __shared__ float sCT[64][68];
    __shared__ float sD[64][68];

    int b = blockIdx.y;
    int q0 = blockIdx.x * 64;
    const float* xc  = x + (size_t)b * P_ * 64;
    const float* d2b = d2 + (size_t)b * P_;

    int t = threadIdx.x;
    int ty = t >> 4, tx = t & 15;
    int w = t >> 6, ln = t & 63;
    int qs = w * 16 + (ln >> 2);
    int cs = ln & 3;

    {
        int qq = t & 63, dg = (t >> 6) * 16;
        const float4* src = (const float4*)(xc + (size_t)(q0 + qq) * 64 + dg);
        float v[16];
        *(float4*)&v[0]  = src[0];
        *(float4*)&v[4]  = src[1];
        *(float4*)&v[8]  = src[2];
        *(float4*)&v[12] = src[3];
#pragma unroll
        for (int i2 = 0; i2 < 16; ++i2) sQT[dg + i2][qq] = v[i2];
    }
    float qd2i[4];
#pragma unroll
    for (int i = 0; i < 4; ++i) qd2i[i] = d2b[q0 + ty * 4 + i];

    double a[K_];
#pragma unroll
    for (int s = 0; s < K_; ++s)
        a[s] = __longlong_as_double((0x7F7FFFFFLL << 32) | (long long)(0xFFFF0000u + s));
    const double BIG = __longlong_as_double((0x7F7FFFFFLL << 32) | 0xFFFFFFF0LL);

#pragma unroll 1
    for (int c0 = 0; c0 < P_; c0 += 64) {
        __syncthreads();
        {
            int cc = t & 63, dg = (t >> 6) * 16;
            const float4* src = (const float4*)(xc + (size_t)(c0 + cc) * 64 + dg);
            float v[16];
            *(float4*)&v[0]  = src[0];
            *(float4*)&v[4]  = src[1];
            *(float4*)&v[8]  = src[2];
            *(float4*)&v[12] = src[3];
#pragma unroll
            for (int i2 = 0; i2 < 16; ++i2) sCT[dg + i2][cc] = v[i2];
        }
        __syncthreads();

        float acc[4][4] = {};
#pragma unroll
        for (int kk = 0; kk < 64; ++kk) {
            float4 aq = *(const float4*)&sQT[kk][ty * 4];
            float4 bc = *(const float4*)&sCT[kk][tx * 4];
            acc[0][0] = fmaf(aq.x, bc.x, acc[0][0]); acc[0][1] = fmaf(aq.x, bc.y, acc[0][1]);
            acc[0][2] = fmaf(aq.x, bc.z, acc[0][2]); acc[0][3] = fmaf(aq.x, bc.w, acc[0][3]);
            acc[1][0] = fmaf(aq.y, bc.x, acc[1][0]); acc[1][1] = fmaf(aq.y, bc.y, acc[1][1]);
            acc[1][2] = fmaf(aq.y, bc.z, acc[1][2]); acc[1][3] = fmaf(aq.y, bc.w, acc[1][3]);
            acc[2][0] = fmaf(aq.z, bc.x, acc[2][0]); acc[2][1] = fmaf(aq.z, bc.y, acc[2][1]);
            acc[2][2] = fmaf(aq.z, bc.z, acc[2][2]); acc[2][3] = fmaf(aq.z, bc.w, acc[2][3]);
            acc[3][0] = fmaf(aq.w, bc.x, acc[3][0]); acc[3][1] = fmaf(aq.w, bc.y, acc[3][1]);
            acc[3][2] = fmaf(aq.w, bc.z, acc[3][2]); acc[3][3] = fmaf(aq.w, bc.w, acc[3][3]);
        }
        float cd2j[4];
#pragma unroll
        for (int j = 0; j < 4; ++j) cd2j[j] = d2b[c0 + tx * 4 + j];
        bool diag = (q0 == c0);
#pragma unroll
        for (int i = 0; i < 4; ++i) {
            float dd[4];
#pragma unroll
            for (int j = 0; j < 4; ++j) {
                float v = (qd2i[i] + cd2j[j]) - 2.f * acc[i][j];
                if (diag && (ty * 4 + i == tx * 4 + j)) v += 1e10f;
                dd[j] = fmaxf(v, 0.f);
            }
            *(float4*)&sD[ty * 4 + i][tx * 4] = make_float4(dd[0], dd[1], dd[2], dd[3]);
        }
        __syncthreads();

#pragma unroll
        for (int u = 0; u < 16; ++u) {
            int c = cs + u * 4;
            float dv = sD[qs][c];
            u64 kb = ((u64)__float_as_uint(dv) << 32) | (u32)(c0 + c);
            double carry = __longlong_as_double((long long)kb);
#pragma unroll
            for (int s = 0; s < K_; ++s) {
                double as = a[s];
                a[s]  = fmin(carry, as);
                carry = fmax(carry, as);
            }
        }
    }

    int* op = idx + ((size_t)(b * P_ + q0 + qs)) * K_;
#pragma unroll 1
    for (int k = 0; k < K_; ++k) {
        double v = a[0];
        double v1 = __shfl_xor(v, 1);
        v = fmin(v, v1);
        double v2 = __shfl_xor(v, 2);
        v = fmin(v, v2);
        bool win = (__double_as_longlong(a[0]) == __double_as_longlong(v));
#pragma unroll
        for (int s = 0; s < K_ - 1; ++s) a[s] = win ? a[s + 1] : a[s];
        a[K_ - 1] = win ? BIG : a[K_ - 1];
        if (cs == 0)
            op[k] = b * P_ + (int)(__double_as_longlong(v) & 0xFFFFFFFFLL);
    }
}

// ---------------------------------------------------------------- pack W[128,64] -> Wpk[64,128], bpk
__global__ __launch_bounds__(128) void pack_kernel(const float* __restrict__ W,
                                                   const float* __restrict__ b,
                                                   float* __restrict__ Wpk,
                                                   float* __restrict__ bpk) {
    int t = blockIdx.x * 128 + threadIdx.x;
    int d = t >> 7, h2 = t & 127;
    Wpk[t] = (h2 < 64) ? W[d * 64 + h2] : W[(64 + d) * 64 + (h2 - 64)];
    if (t < 128) bpk[t] = (t < 64) ? b[t] : 0.f;
}

// ---------------------------------------------------------------- layer-1 UV (D=3, direct)
__global__ __launch_bounds__(256) void uv3_kernel(const float* __restrict__ x,
                                                  const float* __restrict__ W,
                                                  const float* __restrict__ b,
                                                  float* __restrict__ UV) {
    int t = blockIdx.x * 256 + threadIdx.x;
    int p = t >> 7, h2 = t & 127;
    float x0 = x[p * 3], x1 = x[p * 3 + 1], x2 = x[p * 3 + 2];
    float r;
    if (h2 < 64) {
        r = b[h2] + x0 * W[h2] + x1 * W[64 + h2] + x2 * W[128 + h2];
    } else {
        int h = h2 - 64;
        r = x0 * W[192 + h] + x1 * W[256 + h] + x2 * W[320 + h];
    }
    UV[t] = r;
}

// ---------------------------------------------------------------- edge max
__global__ __launch_bounds__(256) void edgemax_kernel(const float* __restrict__ UV,
                                                      const int* __restrict__ idx,
                                                      float* __restrict__ xout) {
    int wv = threadIdx.x >> 6, lane = threadIdx.x & 63;
    int p = blockIdx.x * 4 + wv;
    const float* uvp = UV + (size_t)p * 128;
    float duv = uvp[lane] - uvp[64 + lane];
    const int* ip = idx + (size_t)p * K_;
    int jj[K_];
#pragma unroll
    for (int k = 0; k < K_; ++k) jj[k] = ip[k];
    float m = -3.4e38f;
#pragma unroll
    for (int k = 0; k < K_; ++k) {
        float vj = UV[(size_t)jj[k] * 128 + 64 + lane];
        float t = duv + vj;
        m = fmaxf(m, fmaxf(t, NEG_SLOPE * t));
    }
    xout[(size_t)p * H_ + lane] = m;
}

// ---------------------------------------------------------------- GEMM 64x64 f32 (UV + Wo)
__global__ __launch_bounds__(256) void gemm_kernel(const float* __restrict__ A1,
                                                   const float* __restrict__ A2,
                                                   const float* __restrict__ A3,
                                                   int cat,
                                                   const float* __restrict__ Wm,
                                                   const float* __restrict__ bias,
                                                   float* __restrict__ Cm,
                                                   int M, int N, int Kd, int leaky) {
    __shared__ float sA[32][68];
    __shared__ float sB[32][68];

    int tid = threadIdx.x;
    int row0 = blockIdx.x * 64, col0 = blockIdx.y * 64;
    int tx = tid & 15, ty = tid >> 4;

    int lr  = tid >> 2;
    int lk4 = (tid & 3) * 4;
    int lkb = tid >> 4;
    int lnb = (tid & 15) * 4;

    float acc[4][4] = {};

    for (int k0 = 0; k0 < Kd; k0 += 32) {
        int arow = row0 + lr;
#pragma unroll
        for (int h = 0; h < 32; h += 16) {
            int kk = k0 + lk4 + h;
            const float* src;
            if (cat) {
                if (kk < 64)       src = A1 + (size_t)arow * 64 + kk;
                else if (kk < 128) src = A2 + (size_t)arow * 64 + (kk - 64);
                else               src = A3 + (size_t)arow * 64 + (kk - 128);
            } else {
                src = A1 + (size_t)arow * Kd + kk;
            }
            float4 av = *(const float4*)src;
            sA[lk4 + h + 0][lr] = av.x; sA[lk4 + h + 1][lr] = av.y;
            sA[lk4 + h + 2][lr] = av.z; sA[lk4 + h + 3][lr] = av.w;
        }
        int bcol = col0 + lnb;
#pragma unroll
        for (int h = 0; h < 32; h += 16) {
            float4 bv = make_float4(0.f, 0.f, 0.f, 0.f);
            if (bcol < N) bv = *(const float4*)(Wm + (size_t)(k0 + lkb + h) * N + bcol);
            *(float4*)&sB[lkb + h][lnb] = bv;
        }
        __syncthreads();

#pragma unroll
        for (int kk2 = 0; kk2 < 32; ++kk2) {
            float4 a = *(const float4*)&sA[kk2][ty * 4];
            float4 bb = *(const float4*)&sB[kk2][tx * 4];
            acc[0][0] = fmaf(a.x, bb.x, acc[0][0]); acc[0][1] = fmaf(a.x, bb.y, acc[0][1]);
            acc[0][2] = fmaf(a.x, bb.z, acc[0][2]); acc[0][3] = fmaf(a.x, bb.w, acc[0][3]);
            acc[1][0] = fmaf(a.y, bb.x, acc[1][0]); acc[1][1] = fmaf(a.y, bb.y, acc[1][1]);
            acc[1][2] = fmaf(a.y, bb.z, acc[1][2]); acc[1][3] = fmaf(a.y, bb.w, acc[1][3]);
            acc[2][0] = fmaf(a.z, bb.x, acc[2][0]); acc[2][1] = fmaf(a.z, bb.y, acc[2][1]);
            acc[2][2] = fmaf(a.z, bb.z, acc[2][2]); acc[2][3] = fmaf(a.z, bb.w, acc[2][3]);
            acc[3][0] = fmaf(a.w, bb.x, acc[3][0]); acc[3][1] = fmaf(a.w, bb.y, acc[3][1]);
            acc[3][2] = fmaf(a.w, bb.z, acc[3][2]); acc[3][3] = fmaf(a.w, bb.w, acc[3][3]);
        }
        __syncthreads();
    }

    for (int i = 0; i < 4; ++i) {
        int row = row0 + ty * 4 + i;
        for (int j = 0; j < 4; ++j) {
            int col = col0 + tx * 4 + j;
            if (col < N) {
                float v = acc[i][j] + bias[col];
                if (leaky) v = v > 0.f ? v : NEG_SLOPE * v;
                Cm[(size_t)row * N + col] = v;
            }
        }
    }
}

// ---------------------------------------------------------------- head: f32 W[K,N] -> bf16 WT[N,K]
__global__ __launch_bounds__(256) void wcvtT_kernel(const float* __restrict__ W,
                                                    u16* __restrict__ WT, int K, int N) {
    int t = blockIdx.x * 256 + threadIdx.x;
    if (t >= K * N) return;
    int k = t / N, n = t % N;
    WT[(size_t)n * K + k] = f2bf(W[t]);
}

// ---------------------------------------------------------------- head: concat(x1,x2,x3) chunk -> bf16 [4096,192]
__global__ __launch_bounds__(256) void cvt_cat_kernel(const float* __restrict__ x1,
                                                      const float* __restrict__ x2,
                                                      const float* __restrict__ x3,
                                                      u16* __restrict__ A0) {
    int t = blockIdx.x * 256 + threadIdx.x;     // 4096*48
    int r = t / 48, c4 = (t % 48) * 4;
    const float* src = (c4 < 64) ? (x1 + (size_t)r * 64 + c4)
                     : (c4 < 128) ? (x2 + (size_t)r * 64 + (c4 - 64))
                                  : (x3 + (size_t)r * 64 + (c4 - 128));
    float4 v = *(const float4*)src;
    u16* dst = A0 + (size_t)r * 192 + c4;
    dst[0] = f2bf(v.x); dst[1] = f2bf(v.y); dst[2] = f2bf(v.z); dst[3] = f2bf(v.w);
}

// ---------------------------------------------------------------- MFMA GEMM: C = act(A @ B + bias)
// A: [4096,KD] bf16 row-major; BT: [N,KD] bf16; 128x128 tile, BK=64, 4 waves 2x2,
// wave = 64x64 = 4x4 frags of mfma_f32_16x16x32_bf16. LDS XOR-swizzled (G4).
template <int KD, int OUT_BF16>
__global__ __launch_bounds__(256) void gemm_mfma_kernel(const u16* __restrict__ A,
                                                        const u16* __restrict__ BT,
                                                        const float* __restrict__ bias,
                                                        void* __restrict__ Cout,
                                                        int N, int leaky) {
    __shared__ u16 sA[128 * 64];   // elem (r,k) at byte r*128 + ((k*2) ^ ((r&7)<<4))
    __shared__ u16 sB[128 * 64];   // elem (n,k) same scheme

    int t = threadIdx.x;
    int wave = t >> 6, lane = t & 63;
    int wm = wave >> 1, wn = wave & 1;
    int row0 = blockIdx.x * 128;
    int col0 = blockIdx.y * 128;

    f32x4 acc[4][4] = {};

    for (int k0 = 0; k0 < KD; k0 += 64) {
        __syncthreads();
#pragma unroll
        for (int i = 0; i < 4; ++i) {
            int li = t + i * 256;
            int r = li >> 3;
            int kc = (li & 7) * 8;
            bf16x8 v = *(const bf16x8*)(A + (size_t)(row0 + r) * KD + k0 + kc);
            *(bf16x8*)((char*)sA + r * 128 + ((kc * 2) ^ ((r & 7) << 4))) = v;
        }
#pragma unroll
        for (int i = 0; i < 4; ++i) {
            int li = t + i * 256;
            int n = li >> 3;
            int kc = (li & 7) * 8;
            bf16x8 v = *(const bf16x8*)(BT + (size_t)(col0 + n) * KD + k0 + kc);
            *(bf16x8*)((char*)sB + n * 128 + ((kc * 2) ^ ((n & 7) << 4))) = v;
        }
        __syncthreads();

#pragma unroll
        for (int kk = 0; kk < 2; ++kk) {
            int kb = kk * 64 + (lane >> 4) * 16;   // byte offset of this lane's 8 bf16
            bf16x8 af[4], bfr[4];
#pragma unroll
            for (int mi = 0; mi < 4; ++mi) {
                int r = wm * 64 + mi * 16 + (lane & 15);
                af[mi] = *(const bf16x8*)((char*)sA + r * 128 + (kb ^ ((r & 7) << 4)));
            }
#pragma unroll
            for (int ni = 0; ni < 4; ++ni) {
                int n = wn * 64 + ni * 16 + (lane & 15);
                bfr[ni] = *(const bf16x8*)((char*)sB + n * 128 + (kb ^ ((n & 7) << 4)));
            }
#pragma unroll
            for (int mi = 0; mi < 4; ++mi)
#pragma unroll
                for (int ni = 0; ni < 4; ++ni)
                    acc[mi][ni] = __builtin_amdgcn_mfma_f32_16x16x32_bf16(
                        af[mi], bfr[ni], acc[mi][ni], 0, 0, 0);
        }
    }

#pragma unroll
    for (int ni = 0; ni < 4; ++ni) {
        int col = col0 + wn * 64 + ni * 16 + (lane & 15);
        float bs = bias[col];
#pragma unroll
        for (int mi = 0; mi < 4; ++mi) {
#pragma unroll
            for (int r = 0; r < 4; ++r) {
                int row = (blockIdx.x * 128) + wm * 64 + mi * 16 + (lane >> 4) * 4 + r;
                float v = acc[mi][ni][r] + bs;
                if (leaky) v = v > 0.f ? v : NEG_SLOPE * v;
                if (OUT_BF16)
                    ((u16*)Cout)[(size_t)row * N + col] = f2bf(v);
                else
                    ((float*)Cout)[(size_t)row * N + col] = v;
            }
        }
    }
}

// ---------------------------------------------------------------- log_softmax rows of 40
__global__ __launch_bounds__(256) void lsm_kernel(float* __restrict__ out) {
    int row = blockIdx.x * 4 + (threadIdx.x >> 6);
    int lane = threadIdx.x & 63;
    float v = -3.4e38f;
    if (lane < C_) v = out[(size_t)row * C_ + lane];
    float m = v;
#pragma unroll
    for (int s = 1; s < 64; s <<= 1) m = fmaxf(m, __shfl_xor(m, s));
    float e = (lane < C_) ? expf(v - m) : 0.f;
    float sum = e;
#pragma unroll
    for (int s = 1; s < 64; s <<= 1) sum += __shfl_xor(sum, s);
    if (lane < C_) out[(size_t)row * C_ + lane] = v - m - logf(sum);
}

// ----------------------------------------------------------------
extern "C" void kernel_launch(void* const* d_in, const int* in_sizes, int n_in,
                              void* d_out, int out_size, void* d_ws, size_t ws_size,
                              hipStream_t stream) {
    const float* x   = (const float*)d_in[0];
    const float* W1  = (const float*)d_in[2];
    const float* b1  = (const float*)d_in[3];
    const float* W2  = (const float*)d_in[4];
    const float* b2  = (const float*)d_in[5];
    const float* W3  = (const float*)d_in[6];
    const float* b3  = (const float*)d_in[7];
    const float* Wl  = (const float*)d_in[8];
    const float* bl  = (const float*)d_in[9];
    const float* Wm1 = (const float*)d_in[10];
    const float* bm1 = (const float*)d_in[11];
    const float* Wm2 = (const float*)d_in[12];
    const float* bm2 = (const float*)d_in[13];
    const float* Wo  = (const float*)d_in[14];
    const float* bo  = (const float*)d_in[15];
    float* out = (float*)d_out;

    // ---- workspace (max 50,987,008 B — proven footprint) ----
    char* ws = (char*)d_ws;
    float* x1   = (float*)(ws);                       // 8 MB
    float* x2   = (float*)(ws + 8388608);             // 8 MB
    float* x3   = (float*)(ws + 16777216);            // 8 MB
    int*   idx  = (int*)  (ws + 25165824);            // 2.62 MB
    float* d2   = (float*)(ws + 27787264);            // 128 KB
    // region 27,918,336 .. 50,987,008 (23 MB), phase-aliased:
    u64*   segl = (u64*)  (ws + 27918336);            // layer-1 knn
    float* UV   = (float*)(ws + 27918336);            // edge phase
    float* Wpk  = (float*)(ws + 44695552);            // edge phase
    float* bpk  = (float*)(ws + 44728320);
    // head phase (UV dead):
    char* hb = ws + 27918336;
    u16*   WlT   = (u16*)(hb);                        // [1024][192]  393,216 B
    u16*   Wm1T  = (u16*)(hb + 393216);               // [256][1024]  524,288 B
    u16*   Wm2T  = (u16*)(hb + 917504);               // [128][256]    65,536 B
    u16*   A0bf  = (u16*)(hb + 983040);               // [4096][192] 1,572,864 B
    u16*   act1  = (u16*)(hb + 2555904);              // [4096][1024] 8,388,608 B
    u16*   act2  = (u16*)(hb + 10944512);             // [4096][256]  2,097,152 B
    float* act3  = (float*)(hb + 13041664);           // [4096][128]  2,097,152 B (f32)

    const int SEG_GRID = (NPT / 64) * NSEG;           // 2048

    // ---- layer 1 (D=3)
    d2_kernel<3><<<NPT / 256, 256, 0, stream>>>(x, d2);
    knn_seg_kernel<3><<<SEG_GRID, 64, 0, stream>>>(x, d2, segl);
    knn_mergeu64_kernel<<<NPT, 64, 0, stream>>>(segl, idx);
    uv3_kernel<<<NPT * 128 / 256, 256, 0, stream>>>(x, W1, b1, UV);
    edgemax_kernel<<<NPT / 4, 256, 0, stream>>>(UV, idx, x1);
    // ---- layer 2 (D=64)
    d2_kernel<64><<<NPT / 256, 256, 0, stream>>>(x1, d2);
    knnf64_kernel<<<dim3(P_ / 64, B_), 256, 0, stream>>>(x1, d2, idx);
    pack_kernel<<<64, 128, 0, stream>>>(W2, b2, Wpk, bpk);
    gemm_kernel<<<dim3(NPT / 64, 2), 256, 0, stream>>>(x1, nullptr, nullptr, 0,
                                                       Wpk, bpk, UV, NPT, 128, 64, 0);
    edgemax_kernel<<<NPT / 4, 256, 0, stream>>>(UV, idx, x2);
    // ---- layer 3 (D=64)
    d2_kernel<64><<<NPT / 256, 256, 0, stream>>>(x2, d2);
    knnf64_kernel<<<dim3(P_ / 64, B_), 256, 0, stream>>>(x2, d2, idx);
    pack_kernel<<<64, 128, 0, stream>>>(W3, b3, Wpk, bpk);
    gemm_kernel<<<dim3(NPT / 64, 2), 256, 0, stream>>>(x2, nullptr, nullptr, 0,
                                                       Wpk, bpk, UV, NPT, 128, 64, 0);
    edgemax_kernel<<<NPT / 4, 256, 0, stream>>>(UV, idx, x3);

    // ---- MLP head: bf16 MFMA (Wl, Wm1, Wm2) + f32 (Wo)
    wcvtT_kernel<<<(192 * 1024 + 255) / 256, 256, 0, stream>>>(Wl, WlT, 192, 1024);
    wcvtT_kernel<<<(1024 * 256 + 255) / 256, 256, 0, stream>>>(Wm1, Wm1T, 1024, 256);
    wcvtT_kernel<<<(256 * 128 + 255) / 256, 256, 0, stream>>>(Wm2, Wm2T, 256, 128);

    for (int c = 0; c < 8; ++c) {
        size_t r0 = (size_t)c * 4096;
        cvt_cat_kernel<<<4096 * 48 / 256, 256, 0, stream>>>(x1 + r0 * 64, x2 + r0 * 64,
                                                            x3 + r0 * 64, A0bf);
        gemm_mfma_kernel<192, 1><<<dim3(32, 8), 256, 0, stream>>>(A0bf, WlT, bl, act1, 1024, 1);
        gemm_mfma_kernel<1024, 1><<<dim3(32, 2), 256, 0, stream>>>(act1, Wm1T, bm1, act2, 256, 1);
        gemm_mfma_kernel<256, 0><<<dim3(32, 1), 256, 0, stream>>>(act2, Wm2T, bm2, act3, 128, 1);
        gemm_kernel<<<dim3(64, 1), 256, 0, stream>>>(act3, nullptr, nullptr,
                                                     0, Wo, bo, out + r0 * C_, 4096, 40, 128, 0);
    }
    lsm_kernel<<<NPT / 4, 256, 0, stream>>>(out);
}

// Round 9
// 1550.521 us; speedup vs baseline: 2.2710x; 1.3084x over previous
//
#include <hip/hip_runtime.h>
#include <cstddef>
#include <cstdint>

constexpr int B_ = 8, P_ = 4096, K_ = 20, H_ = 64, C_ = 40;
constexpr int NPT = B_ * P_;
#define NEG_SLOPE 0.2f

typedef unsigned long long u64;
typedef unsigned int u32;
typedef unsigned short u16;
typedef __attribute__((ext_vector_type(8))) short bf16x8;
typedef __attribute__((ext_vector_type(4))) float f32x4;

__device__ inline u16 f2bf(float v) {   // round-to-nearest-even bf16
    u32 bits = __float_as_uint(v);
    return (u16)((bits + 0x7FFFu + ((bits >> 16) & 1)) >> 16);
}

// ---------------------------------------------------------------- d2 = sum(x*x)
template <int D>
__global__ __launch_bounds__(256) void d2_kernel(const float* __restrict__ x,
                                                 float* __restrict__ d2) {
    int i = blockIdx.x * 256 + threadIdx.x;
    if (i >= NPT) return;
    const float* r = x + (size_t)i * D;
    float s = 0.f;
    if constexpr (D % 4 == 0) {
#pragma unroll
        for (int d = 0; d < D; d += 4) {
            float4 v = *(const float4*)(r + d);
            s += v.x * v.x + v.y * v.y + v.z * v.z + v.w * v.w;
        }
    } else {
#pragma unroll
        for (int d = 0; d < D; ++d) { float v = r[d]; s += v * v; }
    }
    d2[i] = s;
}

// ---------------------------------------------------------------- fused knn:
// block = 64 queries vs all 4096 candidates of batch b.
// Per 64-cand chunk: dist tile via LDS GEMM (4x4 microtile, D iters),
// then 4-lanes-per-query exact sorted-top20 (f64-packed keys) with
// depth-2 pending buffer gating the 20-slot fmin/fmax bubble (R4 scheme).
template <int D>
__global__ __launch_bounds__(256) void knnf_kernel(const float* __restrict__ x,
                                                   const float* __restrict__ d2,
                                                   int* __restrict__ idx) {
    __shared__ float sQT[D][68];    // [d][q]
    __shared__ float sCT[D][68];    // [d][c]
    __shared__ float sD[64][68];    // [q][c]

    int b = blockIdx.y;
    int q0 = blockIdx.x * 64;
    const float* xc  = x + (size_t)b * P_ * D;
    const float* d2b = d2 + (size_t)b * P_;

    int t = threadIdx.x;
    int ty = t >> 4, tx = t & 15;
    int w = t >> 6, ln = t & 63;
    int qs = w * 16 + (ln >> 2);     // selection: query row in tile
    int cs = ln & 3;                 // selection: candidate sub-stream

    // stage Q^T once
    if constexpr (D == 64) {
        int qq = t & 63, dg = (t >> 6) * 16;
        const float4* src = (const float4*)(xc + (size_t)(q0 + qq) * 64 + dg);
        float v[16];
        *(float4*)&v[0]  = src[0];
        *(float4*)&v[4]  = src[1];
        *(float4*)&v[8]  = src[2];
        *(float4*)&v[12] = src[3];
#pragma unroll
        for (int i2 = 0; i2 < 16; ++i2) sQT[dg + i2][qq] = v[i2];
    } else {
        if (t < 64) {
#pragma unroll
            for (int d = 0; d < D; ++d) sQT[d][t] = xc[(size_t)(q0 + t) * D + d];
        }
    }
    float qd2i[4];
#pragma unroll
    for (int i = 0; i < 4; ++i) qd2i[i] = d2b[q0 + ty * 4 + i];

    // sorted ascending top-20 as positive doubles (bitwise == (dist_bits<<32)|cand)
    double a[K_];
#pragma unroll
    for (int s = 0; s < K_; ++s)
        a[s] = __longlong_as_double((0x7F7FFFFFLL << 32) | (long long)(0xFFFF0000u + s));
    const double BIG  = __longlong_as_double((0x7F7FFFFFLL << 32) | 0xFFFFFFF0LL);
    const double PINV = __longlong_as_double(0x7FE0000000000000LL);  // finite, > any key; bubble no-op

    double p0 = PINV, p1 = PINV;
    int pcnt = 0;

#pragma unroll 1
    for (int c0 = 0; c0 < P_; c0 += 64) {
        __syncthreads();   // prev GEMM sCT-reads + prev selection sD-reads complete
        if constexpr (D == 64) {
            int cc = t & 63, dg = (t >> 6) * 16;
            const float4* src = (const float4*)(xc + (size_t)(c0 + cc) * 64 + dg);
            float v[16];
            *(float4*)&v[0]  = src[0];
            *(float4*)&v[4]  = src[1];
            *(float4*)&v[8]  = src[2];
            *(float4*)&v[12] = src[3];
#pragma unroll
            for (int i2 = 0; i2 < 16; ++i2) sCT[dg + i2][cc] = v[i2];
        } else {
            if (t < 64) {
#pragma unroll
                for (int d = 0; d < D; ++d) sCT[d][t] = xc[(size_t)(c0 + t) * D + d];
            }
        }
        __syncthreads();   // sCT ready

        float acc[4][4] = {};
#pragma unroll
        for (int kk = 0; kk < D; ++kk) {
            float4 aq = *(const float4*)&sQT[kk][ty * 4];
            float4 bc = *(const float4*)&sCT[kk][tx * 4];
            acc[0][0] = fmaf(aq.x, bc.x, acc[0][0]); acc[0][1] = fmaf(aq.x, bc.y, acc[0][1]);
            acc[0][2] = fmaf(aq.x, bc.z, acc[0][2]); acc[0][3] = fmaf(aq.x, bc.w, acc[0][3]);
            acc[1][0] = fmaf(aq.y, bc.x, acc[1][0]); acc[1][1] = fmaf(aq.y, bc.y, acc[1][1]);
            acc[1][2] = fmaf(aq.y, bc.z, acc[1][2]); acc[1][3] = fmaf(aq.y, bc.w, acc[1][3]);
            acc[2][0] = fmaf(aq.z, bc.x, acc[2][0]); acc[2][1] = fmaf(aq.z, bc.y, acc[2][1]);
            acc[2][2] = fmaf(aq.z, bc.z, acc[2][2]); acc[2][3] = fmaf(aq.z, bc.w, acc[2][3]);
            acc[3][0] = fmaf(aq.w, bc.x, acc[3][0]); acc[3][1] = fmaf(aq.w, bc.y, acc[3][1]);
            acc[3][2] = fmaf(aq.w, bc.z, acc[3][2]); acc[3][3] = fmaf(aq.w, bc.w, acc[3][3]);
        }
        float cd2j[4];
#pragma unroll
        for (int j = 0; j < 4; ++j) cd2j[j] = d2b[c0 + tx * 4 + j];
        bool diag = (q0 == c0);
#pragma unroll
        for (int i = 0; i < 4; ++i) {
            float dd[4];
#pragma unroll
            for (int j = 0; j < 4; ++j) {
                float v = (qd2i[i] + cd2j[j]) - 2.f * acc[i][j];
                if (diag && (ty * 4 + i == tx * 4 + j)) v += 1e10f;   // self mask
                dd[j] = fmaxf(v, 0.f);                                // keep key monotonic
            }
            *(float4*)&sD[ty * 4 + i][tx * 4] = make_float4(dd[0], dd[1], dd[2], dd[3]);
        }
        __syncthreads();   // sD ready

        // selection: 16 evals/lane; bubble only on flush (depth-2 pending)
#pragma unroll
        for (int u = 0; u < 16; ++u) {
            int c = cs + u * 4;
            float dv = sD[qs][c];
            u64 kb = ((u64)__float_as_uint(dv) << 32) | (u32)(c0 + c);
            double key = __longlong_as_double((long long)kb);

            bool pass = key < a[K_ - 1];     // conservative gate (a[19] stale-high)
            p1 = pass ? p0 : p1;
            p0 = pass ? key : p0;
            pcnt = pass ? pcnt + 1 : pcnt;

            if (__any(pcnt >= 2)) {
                double carry = p1;
#pragma unroll
                for (int s = 0; s < K_; ++s) {
                    double as = a[s];
                    a[s]  = fmin(carry, as);
                    carry = fmax(carry, as);
                }
                carry = p0;
#pragma unroll
                for (int s = 0; s < K_; ++s) {
                    double as = a[s];
                    a[s]  = fmin(carry, as);
                    carry = fmax(carry, as);
                }
                p0 = PINV; p1 = PINV; pcnt = 0;
            }
        }
    }
    // final flush of leftovers
    {
        double carry = p1;
#pragma unroll
        for (int s = 0; s < K_; ++s) {
            double as = a[s];
            a[s]  = fmin(carry, as);
            carry = fmax(carry, as);
        }
        carry = p0;
#pragma unroll
        for (int s = 0; s < K_; ++s) {
            double as = a[s];
            a[s]  = fmin(carry, as);
            carry = fmax(carry, as);
        }
    }

    // merge the 4 sub-stream lists per query: 20 rounds pop-min
    int* op = idx + ((size_t)(b * P_ + q0 + qs)) * K_;
#pragma unroll 1
    for (int k = 0; k < K_; ++k) {
        double v = a[0];
        double v1 = __shfl_xor(v, 1);
        v = fmin(v, v1);
        double v2 = __shfl_xor(v, 2);
        v = fmin(v, v2);
        bool win = (__double_as_longlong(a[0]) == __double_as_longlong(v));
#pragma unroll
        for (int s = 0; s < K_ - 1; ++s) a[s] = win ? a[s + 1] : a[s];
        a[K_ - 1] = win ? BIG : a[K_ - 1];
        if (cs == 0)
            op[k] = b * P_ + (int)(__double_as_longlong(v) & 0xFFFFFFFFLL);
    }
}

// ---------------------------------------------------------------- pack W[128,64] -> Wpk[64,128], bpk
__global__ __launch_bounds__(128) void pack_kernel(const float* __restrict__ W,
                                                   const float* __restrict__ b,
                                                   float* __restrict__ Wpk,
                                                   float* __restrict__ bpk) {
    int t = blockIdx.x * 128 + threadIdx.x;
    int d = t >> 7, h2 = t & 127;
    Wpk[t] = (h2 < 64) ? W[d * 64 + h2] : W[(64 + d) * 64 + (h2 - 64)];
    if (t < 128) bpk[t] = (t < 64) ? b[t] : 0.f;
}

// ---------------------------------------------------------------- layer-1 UV (D=3, direct)
__global__ __launch_bounds__(256) void uv3_kernel(const float* __restrict__ x,
                                                  const float* __restrict__ W,
                                                  const float* __restrict__ b,
                                                  float* __restrict__ UV) {
    int t = blockIdx.x * 256 + threadIdx.x;
    int p = t >> 7, h2 = t & 127;
    float x0 = x[p * 3], x1 = x[p * 3 + 1], x2 = x[p * 3 + 2];
    float r;
    if (h2 < 64) {
        r = b[h2] + x0 * W[h2] + x1 * W[64 + h2] + x2 * W[128 + h2];
    } else {
        int h = h2 - 64;
        r = x0 * W[192 + h] + x1 * W[256 + h] + x2 * W[320 + h];
    }
    UV[t] = r;
}

// ---------------------------------------------------------------- edge max
__global__ __launch_bounds__(256) void edgemax_kernel(const float* __restrict__ UV,
                                                      const int* __restrict__ idx,
                                                      float* __restrict__ xout) {
    int wv = threadIdx.x >> 6, lane = threadIdx.x & 63;
    int p = blockIdx.x * 4 + wv;
    const float* uvp = UV + (size_t)p * 128;
    float duv = uvp[lane] - uvp[64 + lane];
    const int* ip = idx + (size_t)p * K_;
    int jj[K_];
#pragma unroll
    for (int k = 0; k < K_; ++k) jj[k] = ip[k];
    float m = -3.4e38f;
#pragma unroll
    for (int k = 0; k < K_; ++k) {
        float vj = UV[(size_t)jj[k] * 128 + 64 + lane];
        float t = duv + vj;
        m = fmaxf(m, fmaxf(t, NEG_SLOPE * t));
    }
    xout[(size_t)p * H_ + lane] = m;
}

// ---------------------------------------------------------------- GEMM 64x64 f32 (UV + Wo)
__global__ __launch_bounds__(256) void gemm_kernel(const float* __restrict__ A1,
                                                   const float* __restrict__ Wm,
                                                   const float* __restrict__ bias,
                                                   float* __restrict__ Cm,
                                                   int M, int N, int Kd, int leaky) {
    __shared__ float sA[32][68];
    __shared__ float sB[32][68];

    int tid = threadIdx.x;
    int row0 = blockIdx.x * 64, col0 = blockIdx.y * 64;
    int tx = tid & 15, ty = tid >> 4;

    int lr  = tid >> 2;
    int lk4 = (tid & 3) * 4;
    int lkb = tid >> 4;
    int lnb = (tid & 15) * 4;

    float acc[4][4] = {};

    for (int k0 = 0; k0 < Kd; k0 += 32) {
        int arow = row0 + lr;
#pragma unroll
        for (int h = 0; h < 32; h += 16) {
            int kk = k0 + lk4 + h;
            const float* src = A1 + (size_t)arow * Kd + kk;
            float4 av = *(const float4*)src;
            sA[lk4 + h + 0][lr] = av.x; sA[lk4 + h + 1][lr] = av.y;
            sA[lk4 + h + 2][lr] = av.z; sA[lk4 + h + 3][lr] = av.w;
        }
        int bcol = col0 + lnb;
#pragma unroll
        for (int h = 0; h < 32; h += 16) {
            float4 bv = make_float4(0.f, 0.f, 0.f, 0.f);
            if (bcol < N) bv = *(const float4*)(Wm + (size_t)(k0 + lkb + h) * N + bcol);
            *(float4*)&sB[lkb + h][lnb] = bv;
        }
        __syncthreads();

#pragma unroll
        for (int kk2 = 0; kk2 < 32; ++kk2) {
            float4 a = *(const float4*)&sA[kk2][ty * 4];
            float4 bb = *(const float4*)&sB[kk2][tx * 4];
            acc[0][0] = fmaf(a.x, bb.x, acc[0][0]); acc[0][1] = fmaf(a.x, bb.y, acc[0][1]);
            acc[0][2] = fmaf(a.x, bb.z, acc[0][2]); acc[0][3] = fmaf(a.x, bb.w, acc[0][3]);
            acc[1][0] = fmaf(a.y, bb.x, acc[1][0]); acc[1][1] = fmaf(a.y, bb.y, acc[1][1]);
            acc[1][2] = fmaf(a.y, bb.z, acc[1][2]); acc[1][3] = fmaf(a.y, bb.w, acc[1][3]);
            acc[2][0] = fmaf(a.z, bb.x, acc[2][0]); acc[2][1] = fmaf(a.z, bb.y, acc[2][1]);
            acc[2][2] = fmaf(a.z, bb.z, acc[2][2]); acc[2][3] = fmaf(a.z, bb.w, acc[2][3]);
            acc[3][0] = fmaf(a.w, bb.x, acc[3][0]); acc[3][1] = fmaf(a.w, bb.y, acc[3][1]);
            acc[3][2] = fmaf(a.w, bb.z, acc[3][2]); acc[3][3] = fmaf(a.w, bb.w, acc[3][3]);
        }
        __syncthreads();
    }

    for (int i = 0; i < 4; ++i) {
        int row = row0 + ty * 4 + i;
        for (int j = 0; j < 4; ++j) {
            int col = col0 + tx * 4 + j;
            if (col < N) {
                float v = acc[i][j] + bias[col];
                if (leaky) v = v > 0.f ? v : NEG_SLOPE * v;
                Cm[(size_t)row * N + col] = v;
            }
        }
    }
}

// ---------------------------------------------------------------- head: f32 W[K,N] -> bf16 WT[N,K]
__global__ __launch_bounds__(256) void wcvtT_kernel(const float* __restrict__ W,
                                                    u16* __restrict__ WT, int K, int N) {
    int t = blockIdx.x * 256 + threadIdx.x;
    if (t >= K * N) return;
    int k = t / N, n = t % N;
    WT[(size_t)n * K + k] = f2bf(W[t]);
}

// ---------------------------------------------------------------- head: concat(x1,x2,x3) chunk -> bf16 [4096,192]
__global__ __launch_bounds__(256) void cvt_cat_kernel(const float* __restrict__ x1,
                                                      const float* __restrict__ x2,
                                                      const float* __restrict__ x3,
                                                      u16* __restrict__ A0) {
    int t = blockIdx.x * 256 + threadIdx.x;     // 4096*48
    int r = t / 48, c4 = (t % 48) * 4;
    const float* src = (c4 < 64) ? (x1 + (size_t)r * 64 + c4)
                     : (c4 < 128) ? (x2 + (size_t)r * 64 + (c4 - 64))
                                  : (x3 + (size_t)r * 64 + (c4 - 128));
    float4 v = *(const float4*)src;
    u16* dst = A0 + (size_t)r * 192 + c4;
    dst[0] = f2bf(v.x); dst[1] = f2bf(v.y); dst[2] = f2bf(v.z); dst[3] = f2bf(v.w);
}

// ---------------------------------------------------------------- MFMA GEMM: C = act(A @ B + bias)
template <int KD, int OUT_BF16>
__global__ __launch_bounds__(256) void gemm_mfma_kernel(const u16* __restrict__ A,
                                                        const u16* __restrict__ BT,
                                                        const float* __restrict__ bias,
                                                        void* __restrict__ Cout,
                                                        int N, int leaky) {
    __shared__ u16 sA[128 * 64];   // elem (r,k) at byte r*128 + ((k*2) ^ ((r&7)<<4))
    __shared__ u16 sB[128 * 64];

    int t = threadIdx.x;
    int wave = t >> 6, lane = t & 63;
    int wm = wave >> 1, wn = wave & 1;
    int row0 = blockIdx.x * 128;
    int col0 = blockIdx.y * 128;

    f32x4 acc[4][4] = {};

    for (int k0 = 0; k0 < KD; k0 += 64) {
        __syncthreads();
#pragma unroll
        for (int i = 0; i < 4; ++i) {
            int li = t + i * 256;
            int r = li >> 3;
            int kc = (li & 7) * 8;
            bf16x8 v = *(const bf16x8*)(A + (size_t)(row0 + r) * KD + k0 + kc);
            *(bf16x8*)((char*)sA + r * 128 + ((kc * 2) ^ ((r & 7) << 4))) = v;
        }
#pragma unroll
        for (int i = 0; i < 4; ++i) {
            int li = t + i * 256;
            int n = li >> 3;
            int kc = (li & 7) * 8;
            bf16x8 v = *(const bf16x8*)(BT + (size_t)(col0 + n) * KD + k0 + kc);
            *(bf16x8*)((char*)sB + n * 128 + ((kc * 2) ^ ((n & 7) << 4))) = v;
        }
        __syncthreads();

#pragma unroll
        for (int kk = 0; kk < 2; ++kk) {
            int kb = kk * 64 + (lane >> 4) * 16;
            bf16x8 af[4], bfr[4];
#pragma unroll
            for (int mi = 0; mi < 4; ++mi) {
                int r = wm * 64 + mi * 16 + (lane & 15);
                af[mi] = *(const bf16x8*)((char*)sA + r * 128 + (kb ^ ((r & 7) << 4)));
            }
#pragma unroll
            for (int ni = 0; ni < 4; ++ni) {
                int n = wn * 64 + ni * 16 + (lane & 15);
                bfr[ni] = *(const bf16x8*)((char*)sB + n * 128 + (kb ^ ((n & 7) << 4)));
            }
#pragma unroll
            for (int mi = 0; mi < 4; ++mi)
#pragma unroll
                for (int ni = 0; ni < 4; ++ni)
                    acc[mi][ni] = __builtin_amdgcn_mfma_f32_16x16x32_bf16(
                        af[mi], bfr[ni], acc[mi][ni], 0, 0, 0);
        }
    }

#pragma unroll
    for (int ni = 0; ni < 4; ++ni) {
        int col = col0 + wn * 64 + ni * 16 + (lane & 15);
        float bs = bias[col];
#pragma unroll
        for (int mi = 0; mi < 4; ++mi) {
#pragma unroll
            for (int r = 0; r < 4; ++r) {
                int row = row0 + wm * 64 + mi * 16 + (lane >> 4) * 4 + r;
                float v = acc[mi][ni][r] + bs;
                if (leaky) v = v > 0.f ? v : NEG_SLOPE * v;
                if (OUT_BF16)
                    ((u16*)Cout)[(size_t)row * N + col] = f2bf(v);
                else
                    ((float*)Cout)[(size_t)row * N + col] = v;
            }
        }
    }
}

// ---------------------------------------------------------------- log_softmax rows of 40
__global__ __launch_bounds__(256) void lsm_kernel(float* __restrict__ out) {
    int row = blockIdx.x * 4 + (threadIdx.x >> 6);
    int lane = threadIdx.x & 63;
    float v = -3.4e38f;
    if (lane < C_) v = out[(size_t)row * C_ + lane];
    float m = v;
#pragma unroll
    for (int s = 1; s < 64; s <<= 1) m = fmaxf(m, __shfl_xor(m, s));
    float e = (lane < C_) ? expf(v - m) : 0.f;
    float sum = e;
#pragma unroll
    for (int s = 1; s < 64; s <<= 1) sum += __shfl_xor(sum, s);
    if (lane < C_) out[(size_t)row * C_ + lane] = v - m - logf(sum);
}

// ----------------------------------------------------------------
extern "C" void kernel_launch(void* const* d_in, const int* in_sizes, int n_in,
                              void* d_out, int out_size, void* d_ws, size_t ws_size,
                              hipStream_t stream) {
    const float* x   = (const float*)d_in[0];
    const float* W1  = (const float*)d_in[2];
    const float* b1  = (const float*)d_in[3];
    const float* W2  = (const float*)d_in[4];
    const float* b2  = (const float*)d_in[5];
    const float* W3  = (const float*)d_in[6];
    const float* b3  = (const float*)d_in[7];
    const float* Wl  = (const float*)d_in[8];
    const float* bl  = (const float*)d_in[9];
    const float* Wm1 = (const float*)d_in[10];
    const float* bm1 = (const float*)d_in[11];
    const float* Wm2 = (const float*)d_in[12];
    const float* bm2 = (const float*)d_in[13];
    const float* Wo  = (const float*)d_in[14];
    const float* bo  = (const float*)d_in[15];
    float* out = (float*)d_out;

    // ---- workspace (max 50,987,008 B — proven footprint) ----
    char* ws = (char*)d_ws;
    float* x1   = (float*)(ws);                       // 8 MB
    float* x2   = (float*)(ws + 8388608);             // 8 MB
    float* x3   = (float*)(ws + 16777216);            // 8 MB
    int*   idx  = (int*)  (ws + 25165824);            // 2.62 MB
    float* d2   = (float*)(ws + 27787264);            // 128 KB
    // region 27,918,336 .. 50,987,008, phase-aliased:
    float* UV   = (float*)(ws + 27918336);            // edge phase, 16 MB
    float* Wpk  = (float*)(ws + 44695552);            // edge phase
    float* bpk  = (float*)(ws + 44728320);
    // head phase (UV dead):
    char* hb = ws + 27918336;
    u16*   WlT   = (u16*)(hb);                        // [1024][192]
    u16*   Wm1T  = (u16*)(hb + 393216);               // [256][1024]
    u16*   Wm2T  = (u16*)(hb + 917504);               // [128][256]
    u16*   A0bf  = (u16*)(hb + 983040);               // [4096][192]
    u16*   act1  = (u16*)(hb + 2555904);              // [4096][1024]
    u16*   act2  = (u16*)(hb + 10944512);             // [4096][256]
    float* act3  = (float*)(hb + 13041664);           // [4096][128] f32

    // ---- layer 1 (D=3)
    d2_kernel<3><<<NPT / 256, 256, 0, stream>>>(x, d2);
    knnf_kernel<3><<<dim3(P_ / 64, B_), 256, 0, stream>>>(x, d2, idx);
    uv3_kernel<<<NPT * 128 / 256, 256, 0, stream>>>(x, W1, b1, UV);
    edgemax_kernel<<<NPT / 4, 256, 0, stream>>>(UV, idx, x1);
    // ---- layer 2 (D=64)
    d2_kernel<64><<<NPT / 256, 256, 0, stream>>>(x1, d2);
    knnf_kernel<64><<<dim3(P_ / 64, B_), 256, 0, stream>>>(x1, d2, idx);
    pack_kernel<<<64, 128, 0, stream>>>(W2, b2, Wpk, bpk);
    gemm_kernel<<<dim3(NPT / 64, 2), 256, 0, stream>>>(x1, Wpk, bpk, UV, NPT, 128, 64, 0);
    edgemax_kernel<<<NPT / 4, 256, 0, stream>>>(UV, idx, x2);
    // ---- layer 3 (D=64)
    d2_kernel<64><<<NPT / 256, 256, 0, stream>>>(x2, d2);
    knnf_kernel<64><<<dim3(P_ / 64, B_), 256, 0, stream>>>(x2, d2, idx);
    pack_kernel<<<64, 128, 0, stream>>>(W3, b3, Wpk, bpk);
    gemm_kernel<<<dim3(NPT / 64, 2), 256, 0, stream>>>(x2, Wpk, bpk, UV, NPT, 128, 64, 0);
    edgemax_kernel<<<NPT / 4, 256, 0, stream>>>(UV, idx, x3);

    // ---- MLP head: bf16 MFMA (Wl, Wm1, Wm2) + f32 (Wo)
    wcvtT_kernel<<<(192 * 1024 + 255) / 256, 256, 0, stream>>>(Wl, WlT, 192, 1024);
    wcvtT_kernel<<<(1024 * 256 + 255) / 256, 256, 0, stream>>>(Wm1, Wm1T, 1024, 256);
    wcvtT_kernel<<<(256 * 128 + 255) / 256, 256, 0, stream>>>(Wm2, Wm2T, 256, 128);

    for (int c = 0; c < 8; ++c) {
        size_t r0 = (size_t)c * 4096;
        cvt_cat_kernel<<<4096 * 48 / 256, 256, 0, stream>>>(x1 + r0 * 64, x2 + r0 * 64,
                                                            x3 + r0 * 64, A0bf);
        gemm_mfma_kernel<192, 1><<<dim3(32, 8), 256, 0, stream>>>(A0bf, WlT, bl, act1, 1024, 1);
        gemm_mfma_kernel<1024, 1><<<dim3(32, 2), 256, 0, stream>>>(act1, Wm1T, bm1, act2, 256, 1);
        gemm_mfma_kernel<256, 0><<<dim3(32, 1), 256, 0, stream>>>(act2, Wm2T, bm2, act3, 128, 1);
        gemm_kernel<<<dim3(64, 1), 256, 0, stream>>>(act3, Wo, bo, out + r0 * C_, 4096, 40, 128, 0);
    }
    lsm_kernel<<<NPT / 4, 256, 0, stream>>>(out);
}